// Round 2
// baseline (2017.601 us; speedup 1.0000x reference)
//
#include <hip/hip_runtime.h>
#include <math.h>

#define B_ 2
#define T_ 4096
#define E_ 1024
#define H_ 16
#define D_ 64
#define P_ 64
#define M_ 8
#define CH_ 128
#define NC_ 32
#define F_ 512
#define BH_ 32
#define BT_ 8192

// ---- workspace layout (f32 units; kv is bf16 occupying 2B/elem) ----
static constexpr size_t SZ_BHTD = (size_t)B_ * H_ * T_ * D_;     // 8,388,608
static constexpr size_t SZ_PRF  = (size_t)B_ * H_ * T_ * M_;     // 1,048,576
static constexpr size_t SZ_KS   = (size_t)NC_ * BH_ * F_;        // 524,288
static constexpr size_t SZ_NRM  = (size_t)NC_ * BH_ * CH_;       // 131,072
static constexpr size_t SZ_KV_E = (size_t)NC_ * BH_ * D_ * F_;   // 33,554,432 bf16 elems

static constexpr size_t OFF_Q   = 0;                  // raw q -> polyq (in place)
static constexpr size_t OFF_K   = OFF_Q + SZ_BHTD;    // raw k -> polyk (in place)
static constexpr size_t OFF_V   = OFF_K + SZ_BHTD;
static constexpr size_t OFF_FQ  = OFF_V + SZ_BHTD;    // prfq
static constexpr size_t OFF_FK  = OFF_FQ + SZ_PRF;    // prfk
static constexpr size_t OFF_KS  = OFF_FK + SZ_PRF;    // ksum chunks -> exclusive prefix
static constexpr size_t OFF_NRM = OFF_KS + SZ_KS;
static constexpr size_t OFF_O   = OFF_NRM + SZ_NRM;
static constexpr size_t OFF_KV  = OFF_O + SZ_BHTD;    // bf16 from here (f32-unit offset)
// total bytes = (OFF_KV)*4 + SZ_KV_E*2 = 145,227,776 + 67,108,864 = 212,336,640 B (~202.5 MiB)

__device__ __forceinline__ float bf2f(unsigned short u) {
  union { unsigned u32; float f; } x; x.u32 = ((unsigned)u) << 16; return x.f;
}
__device__ __forceinline__ unsigned short f2bf(float f) {
  union { float f; unsigned u; } x; x.f = f;
  unsigned r = x.u + 0x7fffu + ((x.u >> 16) & 1u);  // round-to-nearest-even
  return (unsigned short)(r >> 16);
}

// ---------------------------------------------------------------------------
// QKV GEMM: C[bt][j] = sum_e x[bt][e]*w[j][e] + b[j], scatter to q/k/v (B,H,T,D)
// ---------------------------------------------------------------------------
__global__ __launch_bounds__(256) void k_qkv(
    const float* __restrict__ x, const float* __restrict__ w,
    const float* __restrict__ bias,
    float* __restrict__ qb, float* __restrict__ kb, float* __restrict__ vb) {
  __shared__ float xs[64][65];   // [kk][tt] transposed, +1 pad
  __shared__ float wsh[64][65];  // [kk][jj]
  const int bt0 = blockIdx.x * 64;
  const int j0  = blockIdx.y * 64;
  const int tid = threadIdx.x;
  const int lr = tid >> 4;
  const int lc = (tid & 15) << 2;
  const int ty = lr, tx = tid & 15;
  float acc[4][4];
#pragma unroll
  for (int i = 0; i < 4; ++i)
#pragma unroll
    for (int j = 0; j < 4; ++j) acc[i][j] = 0.f;

  for (int k0 = 0; k0 < E_; k0 += 64) {
#pragma unroll
    for (int rr = 0; rr < 64; rr += 16) {
      float4 xv = *(const float4*)(x + (size_t)(bt0 + rr + lr) * E_ + k0 + lc);
      xs[lc + 0][rr + lr] = xv.x; xs[lc + 1][rr + lr] = xv.y;
      xs[lc + 2][rr + lr] = xv.z; xs[lc + 3][rr + lr] = xv.w;
      float4 wv = *(const float4*)(w + (size_t)(j0 + rr + lr) * E_ + k0 + lc);
      wsh[lc + 0][rr + lr] = wv.x; wsh[lc + 1][rr + lr] = wv.y;
      wsh[lc + 2][rr + lr] = wv.z; wsh[lc + 3][rr + lr] = wv.w;
    }
    __syncthreads();
#pragma unroll 8
    for (int kk = 0; kk < 64; ++kk) {
      const float a0 = xs[kk][ty * 4 + 0], a1 = xs[kk][ty * 4 + 1];
      const float a2 = xs[kk][ty * 4 + 2], a3 = xs[kk][ty * 4 + 3];
      const float b0 = wsh[kk][tx * 4 + 0], b1 = wsh[kk][tx * 4 + 1];
      const float b2 = wsh[kk][tx * 4 + 2], b3 = wsh[kk][tx * 4 + 3];
      acc[0][0] += a0 * b0; acc[0][1] += a0 * b1; acc[0][2] += a0 * b2; acc[0][3] += a0 * b3;
      acc[1][0] += a1 * b0; acc[1][1] += a1 * b1; acc[1][2] += a1 * b2; acc[1][3] += a1 * b3;
      acc[2][0] += a2 * b0; acc[2][1] += a2 * b1; acc[2][2] += a2 * b2; acc[2][3] += a2 * b3;
      acc[3][0] += a3 * b0; acc[3][1] += a3 * b1; acc[3][2] += a3 * b2; acc[3][3] += a3 * b3;
    }
    __syncthreads();
  }
  const int j = j0 + tx * 4;
  const int sec = j >> 10;          // 0=q,1=k,2=v
  const int jj = j & 1023;
  const int h = jj >> 6;
  const int d4 = jj & 63;
  float* dst = (sec == 0) ? qb : ((sec == 1) ? kb : vb);
  const float b0 = bias[j + 0], b1 = bias[j + 1], b2 = bias[j + 2], b3 = bias[j + 3];
#pragma unroll
  for (int i = 0; i < 4; ++i) {
    const int bt = bt0 + ty * 4 + i;
    const int b = bt >> 12, t = bt & (T_ - 1);
    float4 r;
    r.x = acc[i][0] + b0; r.y = acc[i][1] + b1;
    r.z = acc[i][2] + b2; r.w = acc[i][3] + b3;
    *(float4*)(dst + ((size_t)(b * H_ + h) * T_ + t) * D_ + d4) = r;
  }
}

// ---------------------------------------------------------------------------
// Features: l2norm rows, then poly[t][p] = (xn.pw)^2/8, prf[t][m] = exp(..)*scale.
// poly_out aliases xin (in-place, block-local safe: LDS copy + syncthreads).
// ---------------------------------------------------------------------------
__global__ __launch_bounds__(256) void k_feat(
    const float* xin, const float* __restrict__ poly_w,
    const float* __restrict__ omega, const float* __restrict__ qnod,
    const float* __restrict__ qwt, float* poly_out, float* __restrict__ prf_out) {
  __shared__ float xs[64][65];
  __shared__ float pw[64][64];
  __shared__ float om[64][8];
  const int blk = blockIdx.x;            // 2048 blocks: bh = blk>>6, 64 t per block
  const int bh = blk >> 6;
  const int t0 = (blk & 63) * 64;
  const int h = bh & (H_ - 1);
  const int tid = threadIdx.x;
  const int lr = tid >> 4, lc = (tid & 15) << 2;
#pragma unroll
  for (int rr = 0; rr < 64; rr += 16) {
    float4 v = *(const float4*)(xin + ((size_t)bh * T_ + t0 + rr + lr) * D_ + lc);
    xs[rr + lr][lc + 0] = v.x; xs[rr + lr][lc + 1] = v.y;
    xs[rr + lr][lc + 2] = v.z; xs[rr + lr][lc + 3] = v.w;
    *(float4*)(&pw[rr + lr][lc]) =
        *(const float4*)(poly_w + (size_t)h * D_ * P_ + (size_t)(rr + lr) * P_ + lc);
  }
  if (tid < 128) {
    *(float4*)(&om[tid >> 1][(tid & 1) * 4]) =
        *(const float4*)(omega + (size_t)h * D_ * M_ + (size_t)(tid >> 1) * M_ + (tid & 1) * 4);
  }
  __syncthreads();
  const int wv = tid >> 6, lane = tid & 63;
  for (int tt = wv * 16; tt < wv * 16 + 16; ++tt) {
    float xv = xs[tt][lane];
    float ssum = xv * xv;
#pragma unroll
    for (int off = 32; off > 0; off >>= 1) ssum += __shfl_xor(ssum, off);
    const float rn = 1.0f / fmaxf(sqrtf(ssum), 1e-12f);
    xs[tt][lane] = xv * rn;
  }
  __syncthreads();
  const int p = tid & 63, tg = tid >> 6;
  for (int k = 0; k < 16; ++k) {
    const int t = tg * 16 + k;
    float a = 0.f;
#pragma unroll
    for (int d = 0; d < 64; ++d) a += xs[t][d] * pw[d][p];
    poly_out[((size_t)bh * T_ + t0 + t) * P_ + p] = a * a * 0.125f;  // ^2 / sqrt(64)
  }
  const float s0 = qnod[0];
  const float sq2 = sqrtf(fmaxf(2.f * s0, 0.f));
  const float scale = sqrtf(fmaxf(qwt[0], 0.f)) * 0.3535533905932738f; // 1/sqrt(8)
  const int m = tid & 7, tq = tid >> 3;
#pragma unroll
  for (int rep = 0; rep < 2; ++rep) {
    const int t = tq + rep * 32;
    float a = 0.f;
#pragma unroll
    for (int d = 0; d < 64; ++d) a += xs[t][d] * om[d][m];
    float z = fminf(fmaxf(a * sq2 - s0, -20.f), 20.f);
    prf_out[((size_t)bh * T_ + t0 + t) * M_ + m] = expf(z) * scale;
  }
}

// ---------------------------------------------------------------------------
// Phase A: per (c,bh): kv_c[d][pm] = sum_t kf[t,pm]*v[t,d] (bf16 out);
// ksum_c[pm] = sum_t kf (f32). Two 64-row passes -> 32 KB LDS.
// ---------------------------------------------------------------------------
__global__ __launch_bounds__(512) void k_phaseA(
    const float* __restrict__ polyk, const float* __restrict__ prfk,
    const float* __restrict__ vbuf, unsigned short* __restrict__ kvch,
    float* __restrict__ ksum) {
  __shared__ float pk[64][64];
  __shared__ float vs[64][64];
  const int bh = blockIdx.x & (BH_ - 1);
  const int c = blockIdx.x >> 5;
  const int tid = threadIdx.x;
  const int lr = tid >> 4, lc = (tid & 15) << 2;   // 32 rows x 16 col-groups
  const int pm = tid, p = pm >> 3, m = pm & 7;
  const float* fkg = prfk + ((size_t)bh * T_ + (size_t)c * CH_) * M_ + m;
  float acc[64];
#pragma unroll
  for (int d = 0; d < 64; ++d) acc[d] = 0.f;
  float ks = 0.f;
  for (int half = 0; half < 2; ++half) {
    __syncthreads();
#pragma unroll
    for (int rr = 0; rr < 64; rr += 32) {
      const int r = rr + lr;
      *(float4*)(&pk[r][lc]) =
          *(const float4*)(polyk + ((size_t)bh * T_ + c * CH_ + half * 64 + r) * P_ + lc);
      *(float4*)(&vs[r][lc]) =
          *(const float4*)(vbuf + ((size_t)bh * T_ + c * CH_ + half * 64 + r) * D_ + lc);
    }
    __syncthreads();
    for (int t = 0; t < 64; ++t) {
      const float kf = pk[t][p] * fkg[(size_t)(half * 64 + t) * M_];
      ks += kf;
#pragma unroll
      for (int j = 0; j < 16; ++j) {
        const float4 v4 = *(const float4*)(&vs[t][j * 4]);
        acc[j * 4 + 0] += kf * v4.x; acc[j * 4 + 1] += kf * v4.y;
        acc[j * 4 + 2] += kf * v4.z; acc[j * 4 + 3] += kf * v4.w;
      }
    }
  }
  const size_t base = (size_t)(c * BH_ + bh) * D_ * F_;
#pragma unroll
  for (int d = 0; d < 64; ++d) kvch[base + (size_t)d * F_ + pm] = f2bf(acc[d]);
  ksum[(size_t)(c * BH_ + bh) * F_ + pm] = ks;
}

// ---------------------------------------------------------------------------
// Exclusive prefix over chunks, in place, bf16 storage / f32 running sum.
// ---------------------------------------------------------------------------
__global__ __launch_bounds__(256) void k_scan_kv(unsigned short* __restrict__ kvch) {
  const size_t s = (size_t)blockIdx.x * 256 + threadIdx.x;  // < BH*D*F = 1,048,576
  const size_t stride = (size_t)BH_ * D_ * F_;
  unsigned short v[NC_];
#pragma unroll
  for (int c = 0; c < NC_; ++c) v[c] = kvch[(size_t)c * stride + s];
  float run = 0.f;
#pragma unroll
  for (int c = 0; c < NC_; ++c) {
    const float t = bf2f(v[c]);
    kvch[(size_t)c * stride + s] = f2bf(run);
    run += t;
  }
}

__global__ __launch_bounds__(256) void k_scan_ks(float* __restrict__ ksum) {
  const int s = blockIdx.x * 256 + threadIdx.x;  // < BH*F = 16384
  const int stride = BH_ * F_;
  float v[NC_];
#pragma unroll
  for (int c = 0; c < NC_; ++c) v[c] = ksum[c * stride + s];
  float run = 0.f;
#pragma unroll
  for (int c = 0; c < NC_; ++c) {
    const float t = v[c];
    ksum[c * stride + s] = run;
    run += t;
  }
}

// ---------------------------------------------------------------------------
// Fused scores+intra: per (c,bh) block. Generates masked score slabs
// S[t][s16] = (pq[t].pk[s])*(fq[t].fk[s]) in LDS, immediately contracts with V.
// Writes o (intra part) and rowsum. No global score buffer.
// ---------------------------------------------------------------------------
__global__ __launch_bounds__(256) void k_sintra(
    const float* __restrict__ polyq, const float* __restrict__ prfq,
    const float* __restrict__ polyk, const float* __restrict__ prfk,
    const float* __restrict__ vbuf, float* __restrict__ obuf,
    float* __restrict__ nrmbuf) {
  __shared__ float pq[CH_][65];   // 33,280 B
  __shared__ float fq[CH_][8];    //  4,096 B
  __shared__ float pk[16][65];    //  4,160 B
  __shared__ float fk[16][8];     //    512 B
  __shared__ float vsl[16][64];   //  4,096 B
  __shared__ float ss[CH_][17];   //  8,704 B   (total 54,848 B)
  const int bh = blockIdx.x & (BH_ - 1);
  const int c = blockIdx.x >> 5;
  const int tid = threadIdx.x;
  const size_t rowQ = (size_t)bh * T_ + (size_t)c * CH_;
  const int lr = tid >> 4, lc = (tid & 15) << 2;
#pragma unroll
  for (int rr = 0; rr < CH_; rr += 16) {
    float4 v = *(const float4*)(polyq + (rowQ + rr + lr) * P_ + lc);
    pq[rr + lr][lc + 0] = v.x; pq[rr + lr][lc + 1] = v.y;
    pq[rr + lr][lc + 2] = v.z; pq[rr + lr][lc + 3] = v.w;
  }
  *(float4*)(&fq[tid >> 1][(tid & 1) * 4]) =
      *(const float4*)(prfq + (rowQ + (tid >> 1)) * M_ + (tid & 1) * 4);

  float acc[32], rs[32];
#pragma unroll
  for (int k = 0; k < 32; ++k) { acc[k] = 0.f; rs[k] = 0.f; }
  const int s16 = tid & 15, tg16 = tid >> 4;   // score-phase layout
  const int d = tid & 63, tg4 = tid >> 6;      // S@V-phase layout

  for (int st = 0; st < 8; ++st) {
    __syncthreads();  // protect prior-slab LDS reads (also covers pq/fq staging)
    {
      const int r = tid >> 4, c4 = (tid & 15) << 2;
      float4 a = *(const float4*)(polyk + (rowQ + st * 16 + r) * P_ + c4);
      pk[r][c4 + 0] = a.x; pk[r][c4 + 1] = a.y;
      pk[r][c4 + 2] = a.z; pk[r][c4 + 3] = a.w;
      *(float4*)(&vsl[r][c4]) =
          *(const float4*)(vbuf + (rowQ + st * 16 + r) * D_ + c4);
      if (tid < 32) {
        *(float4*)(&fk[tid >> 1][(tid & 1) * 4]) =
            *(const float4*)(prfk + (rowQ + st * 16 + (tid >> 1)) * M_ + (tid & 1) * 4);
      }
    }
    __syncthreads();
    // scores: thread (s16, tg16) -> 8 t-rows each
    {
      float pkr[64];
#pragma unroll
      for (int p2 = 0; p2 < 64; ++p2) pkr[p2] = pk[s16][p2];
      const float f0 = fk[s16][0], f1 = fk[s16][1], f2 = fk[s16][2], f3 = fk[s16][3];
      const float f4 = fk[s16][4], f5 = fk[s16][5], f6 = fk[s16][6], f7 = fk[s16][7];
      const int sg = st * 16 + s16;
#pragma unroll
      for (int r = 0; r < 8; ++r) {
        const int t = tg16 * 8 + r;
        float aP = 0.f;
#pragma unroll
        for (int p2 = 0; p2 < 64; ++p2) aP += pq[t][p2] * pkr[p2];
        const float aM = fq[t][0] * f0 + fq[t][1] * f1 + fq[t][2] * f2 + fq[t][3] * f3 +
                         fq[t][4] * f4 + fq[t][5] * f5 + fq[t][6] * f6 + fq[t][7] * f7;
        ss[t][s16] = (sg <= t) ? aP * aM : 0.f;
      }
    }
    __syncthreads();
    // S@V: thread (d, tg4) handles t = k*4 + tg4 (interleaved -> bank-clean)
    for (int sj = 0; sj < 16; ++sj) {
      const float vd = vsl[sj][d];
#pragma unroll
      for (int k = 0; k < 32; ++k) {
        const float sv = ss[(k << 2) | tg4][sj];
        acc[k] += sv * vd;
        rs[k] += sv;
      }
    }
  }
  const size_t nbase = (size_t)(c * BH_ + bh) * CH_;
#pragma unroll
  for (int k = 0; k < 32; ++k) {
    const int t = (k << 2) | tg4;
    obuf[(rowQ + t) * D_ + d] = acc[k];
    if (d == 0) nrmbuf[nbase + t] = rs[k];
  }
}

// ---------------------------------------------------------------------------
// Hist + finalize: ch[t][d] = sum_pm qf[t,pm]*kvpref[d][pm] (kv bf16);
// nh[t] = sum_pm qf[t,pm]*kspref[pm]; o = (ci+ch)/(nh+rowsum+DELTA).
// ---------------------------------------------------------------------------
__global__ __launch_bounds__(256) void k_hist(
    const float* __restrict__ polyq, const float* __restrict__ prfq,
    const unsigned short* __restrict__ kvch, const float* __restrict__ ksum,
    const float* __restrict__ nrmbuf, float* __restrict__ obuf) {
  __shared__ float pq[CH_][64];
  __shared__ float fq[CH_][8];
  __shared__ float kvt[64][65];
  __shared__ float kp[F_];
  __shared__ float nhs[CH_];
  const int bh = blockIdx.x & (BH_ - 1);
  const int c = blockIdx.x >> 5;
  const int tid = threadIdx.x;
  const int lr = tid >> 4, lc = (tid & 15) << 2;
#pragma unroll
  for (int rr = 0; rr < CH_; rr += 16)
    *(float4*)(&pq[rr + lr][lc]) =
        *(const float4*)(polyq + ((size_t)bh * T_ + c * CH_ + rr + lr) * P_ + lc);
  *(float4*)(&fq[tid >> 1][(tid & 1) * 4]) =
      *(const float4*)(prfq + ((size_t)bh * T_ + c * CH_ + (tid >> 1)) * M_ + (tid & 1) * 4);
  if (tid < 128)
    *(float4*)(&kp[tid * 4]) =
        *(const float4*)(ksum + (size_t)(c * BH_ + bh) * F_ + tid * 4);
  __syncthreads();
  if (tid < CH_) {
    const int t = tid;
    float fr[8];
#pragma unroll
    for (int mm = 0; mm < 8; ++mm) fr[mm] = fq[t][mm];
    float nh = 0.f;
#pragma unroll
    for (int p2 = 0; p2 < 64; ++p2) {
      float tmp = 0.f;
#pragma unroll
      for (int mm = 0; mm < 8; ++mm) tmp += fr[mm] * kp[p2 * 8 + mm];
      nh += pq[t][p2] * tmp;
    }
    nhs[t] = nh;
  }
  const int d = tid & 63, tg = tid >> 6;
  float ch[32];
#pragma unroll
  for (int k = 0; k < 32; ++k) ch[k] = 0.f;
  const size_t kvbase = (size_t)(c * BH_ + bh) * D_ * F_;
  for (int pmt = 0; pmt < 8; ++pmt) {
    __syncthreads();
#pragma unroll
    for (int rr = 0; rr < 64; rr += 16) {
      const ushort4 u = *(const ushort4*)(kvch + kvbase + (size_t)(rr + lr) * F_ + pmt * 64 + lc);
      kvt[rr + lr][lc + 0] = bf2f(u.x); kvt[rr + lr][lc + 1] = bf2f(u.y);
      kvt[rr + lr][lc + 2] = bf2f(u.z); kvt[rr + lr][lc + 3] = bf2f(u.w);
    }
    __syncthreads();
#pragma unroll
    for (int k = 0; k < 32; ++k) {
      const int t = tg * 32 + k;
      const float f0 = fq[t][0], f1 = fq[t][1], f2 = fq[t][2], f3 = fq[t][3];
      const float f4 = fq[t][4], f5 = fq[t][5], f6 = fq[t][6], f7 = fq[t][7];
      float a = 0.f;
#pragma unroll
      for (int pl = 0; pl < 8; ++pl) {
        const int pb = pl * 8;
        float tmp = f0 * kvt[d][pb + 0] + f1 * kvt[d][pb + 1] +
                    f2 * kvt[d][pb + 2] + f3 * kvt[d][pb + 3] +
                    f4 * kvt[d][pb + 4] + f5 * kvt[d][pb + 5] +
                    f6 * kvt[d][pb + 6] + f7 * kvt[d][pb + 7];
        a += pq[t][pmt * 8 + pl] * tmp;
      }
      ch[k] += a;
    }
  }
  const size_t obase = ((size_t)bh * T_ + c * CH_) * D_;
  const size_t nbase = (size_t)(c * BH_ + bh) * CH_;
#pragma unroll
  for (int k = 0; k < 32; ++k) {
    const int t = tg * 32 + k;
    const float nrm = nhs[t] + nrmbuf[nbase + t] + 1e-6f;
    const size_t oi = obase + (size_t)t * D_ + d;
    obuf[oi] = (obuf[oi] + ch[k]) / nrm;
  }
}

// ---------------------------------------------------------------------------
// Out GEMM: out[bt][e] = sum_{e'} o[b][e'/64][t][e'%64] * ow[e][e'] + ob[e]
// ---------------------------------------------------------------------------
__global__ __launch_bounds__(256) void k_out(
    const float* __restrict__ obuf, const float* __restrict__ w,
    const float* __restrict__ bias, float* __restrict__ out) {
  __shared__ float xs[64][65];
  __shared__ float wsh[64][65];
  const int bt0 = blockIdx.x * 64;
  const int j0  = blockIdx.y * 64;
  const int tid = threadIdx.x;
  const int lr = tid >> 4;
  const int lc = (tid & 15) << 2;
  const int ty = lr, tx = tid & 15;
  float acc[4][4];
#pragma unroll
  for (int i = 0; i < 4; ++i)
#pragma unroll
    for (int j = 0; j < 4; ++j) acc[i][j] = 0.f;

  for (int k0 = 0; k0 < E_; k0 += 64) {
    const int hh = k0 >> 6;
#pragma unroll
    for (int rr = 0; rr < 64; rr += 16) {
      const int bt = bt0 + rr + lr;
      const int b = bt >> 12, t = bt & (T_ - 1);
      float4 xv = *(const float4*)(obuf + ((size_t)(b * H_ + hh) * T_ + t) * D_ + lc);
      xs[lc + 0][rr + lr] = xv.x; xs[lc + 1][rr + lr] = xv.y;
      xs[lc + 2][rr + lr] = xv.z; xs[lc + 3][rr + lr] = xv.w;
      float4 wv = *(const float4*)(w + (size_t)(j0 + rr + lr) * E_ + k0 + lc);
      wsh[lc + 0][rr + lr] = wv.x; wsh[lc + 1][rr + lr] = wv.y;
      wsh[lc + 2][rr + lr] = wv.z; wsh[lc + 3][rr + lr] = wv.w;
    }
    __syncthreads();
#pragma unroll 8
    for (int kk = 0; kk < 64; ++kk) {
      const float a0 = xs[kk][ty * 4 + 0], a1 = xs[kk][ty * 4 + 1];
      const float a2 = xs[kk][ty * 4 + 2], a3 = xs[kk][ty * 4 + 3];
      const float b0 = wsh[kk][tx * 4 + 0], b1 = wsh[kk][tx * 4 + 1];
      const float b2 = wsh[kk][tx * 4 + 2], b3 = wsh[kk][tx * 4 + 3];
      acc[0][0] += a0 * b0; acc[0][1] += a0 * b1; acc[0][2] += a0 * b2; acc[0][3] += a0 * b3;
      acc[1][0] += a1 * b0; acc[1][1] += a1 * b1; acc[1][2] += a1 * b2; acc[1][3] += a1 * b3;
      acc[2][0] += a2 * b0; acc[2][1] += a2 * b1; acc[2][2] += a2 * b2; acc[2][3] += a2 * b3;
      acc[3][0] += a3 * b0; acc[3][1] += a3 * b1; acc[3][2] += a3 * b2; acc[3][3] += a3 * b3;
    }
    __syncthreads();
  }
  const int j = j0 + tx * 4;
  const float b0 = bias[j + 0], b1 = bias[j + 1], b2 = bias[j + 2], b3 = bias[j + 3];
#pragma unroll
  for (int i = 0; i < 4; ++i) {
    const int bt = bt0 + ty * 4 + i;
    float4 r;
    r.x = acc[i][0] + b0; r.y = acc[i][1] + b1;
    r.z = acc[i][2] + b2; r.w = acc[i][3] + b3;
    *(float4*)(out + (size_t)bt * E_ + j) = r;
  }
}

// ---------------------------------------------------------------------------
extern "C" void kernel_launch(void* const* d_in, const int* in_sizes, int n_in,
                              void* d_out, int out_size, void* d_ws, size_t ws_size,
                              hipStream_t stream) {
  (void)in_sizes; (void)n_in; (void)out_size; (void)ws_size;
  const float* x      = (const float*)d_in[0];
  const float* qkv_w  = (const float*)d_in[1];
  const float* qkv_b  = (const float*)d_in[2];
  const float* out_w  = (const float*)d_in[3];
  const float* out_b  = (const float*)d_in[4];
  const float* omega  = (const float*)d_in[5];
  const float* poly_w = (const float*)d_in[6];
  const float* qnod   = (const float*)d_in[7];
  const float* qwt    = (const float*)d_in[8];
  float* ws = (float*)d_ws;
  float* qb   = ws + OFF_Q;
  float* kb   = ws + OFF_K;
  float* vb   = ws + OFF_V;
  float* fqb  = ws + OFF_FQ;
  float* fkb  = ws + OFF_FK;
  float* ksb  = ws + OFF_KS;
  float* nrmb = ws + OFF_NRM;
  float* ob   = ws + OFF_O;
  unsigned short* kvb = (unsigned short*)(ws + OFF_KV);
  float* outp = (float*)d_out;

  hipLaunchKernelGGL(k_qkv, dim3(BT_ / 64, 48), dim3(256), 0, stream,
                     x, qkv_w, qkv_b, qb, kb, vb);
  hipLaunchKernelGGL(k_feat, dim3(2048), dim3(256), 0, stream,
                     qb, poly_w, omega, qnod, qwt, qb, fqb);
  hipLaunchKernelGGL(k_feat, dim3(2048), dim3(256), 0, stream,
                     kb, poly_w, omega, qnod, qwt, kb, fkb);
  hipLaunchKernelGGL(k_phaseA, dim3(NC_ * BH_), dim3(512), 0, stream,
                     kb, fkb, vb, kvb, ksb);
  hipLaunchKernelGGL(k_scan_kv, dim3(4096), dim3(256), 0, stream, kvb);
  hipLaunchKernelGGL(k_scan_ks, dim3(64), dim3(256), 0, stream, ksb);
  hipLaunchKernelGGL(k_sintra, dim3(NC_ * BH_), dim3(256), 0, stream,
                     qb, fqb, kb, fkb, vb, ob, nrmb);
  hipLaunchKernelGGL(k_hist, dim3(NC_ * BH_), dim3(256), 0, stream,
                     qb, fqb, kvb, ksb, nrmb, ob);
  hipLaunchKernelGGL(k_out, dim3(BT_ / 64, E_ / 64), dim3(256), 0, stream,
                     ob, out_w, out_b, outp);
}

// Round 3
// 917.397 us; speedup vs baseline: 2.1993x; 2.1993x over previous
//
#include <hip/hip_runtime.h>
#include <math.h>

#define B_ 2
#define T_ 4096
#define E_ 1024
#define H_ 16
#define D_ 64
#define P_ 64
#define M_ 8
#define CH_ 128
#define NC_ 32
#define F_ 512
#define BH_ 32
#define BT_ 8192

// ---- workspace layout (f32 units; kv is bf16 occupying 2B/elem) ----
static constexpr size_t SZ_BHTD = (size_t)B_ * H_ * T_ * D_;     // 8,388,608
static constexpr size_t SZ_PRF  = (size_t)B_ * H_ * T_ * M_;     // 1,048,576
static constexpr size_t SZ_KS   = (size_t)NC_ * BH_ * F_;        // 524,288
static constexpr size_t SZ_NRM  = (size_t)NC_ * BH_ * CH_;       // 131,072
static constexpr size_t SZ_KV_E = (size_t)NC_ * BH_ * D_ * F_;   // 33,554,432 bf16 elems

static constexpr size_t OFF_Q   = 0;                  // raw q -> polyq (in place)
static constexpr size_t OFF_K   = OFF_Q + SZ_BHTD;    // raw k -> polyk; later o_bf16 overlay
static constexpr size_t OFF_V   = OFF_K + SZ_BHTD;    // v; later out_w bf16 overlay
static constexpr size_t OFF_FQ  = OFF_V + SZ_BHTD;    // prfq
static constexpr size_t OFF_FK  = OFF_FQ + SZ_PRF;    // prfk
static constexpr size_t OFF_KS  = OFF_FK + SZ_PRF;    // ksum chunks -> exclusive prefix
static constexpr size_t OFF_NRM = OFF_KS + SZ_KS;
static constexpr size_t OFF_O   = OFF_NRM + SZ_NRM;   // intra ctx (f32)
static constexpr size_t OFF_KV  = OFF_O + SZ_BHTD;    // bf16 kv region; pre-qkv overlay: x_hi/x_lo/w_bf
// total bytes = OFF_KV*4 + SZ_KV_E*2 = 212,336,640 B (~202.5 MiB) — same as round 2

__device__ __forceinline__ float bf2f(unsigned short u) {
  union { unsigned u32; float f; } x; x.u32 = ((unsigned)u) << 16; return x.f;
}
__device__ __forceinline__ unsigned short f2bf(float f) {
  union { float f; unsigned u; } x; x.f = f;
  unsigned r = x.u + 0x7fffu + ((x.u >> 16) & 1u);  // round-to-nearest-even
  return (unsigned short)(r >> 16);
}

typedef short v8s __attribute__((ext_vector_type(8)));
typedef float f32x4 __attribute__((ext_vector_type(4)));
#define LDSA 72   // padded LDS row stride (bf16 elems): 144 B = 36 dwords -> bank-balanced

// ---------------------------------------------------------------------------
// Cast helpers
// ---------------------------------------------------------------------------
__global__ __launch_bounds__(256) void k_split_x(
    const float* __restrict__ x, unsigned short* __restrict__ hi,
    unsigned short* __restrict__ lo) {
  const size_t i4 = ((size_t)blockIdx.x * 256 + threadIdx.x) * 4;  // < 8,388,608
  const float4 v = *(const float4*)(x + i4);
  ushort4 h, l;
  h.x = f2bf(v.x); l.x = f2bf(v.x - bf2f(h.x));
  h.y = f2bf(v.y); l.y = f2bf(v.y - bf2f(h.y));
  h.z = f2bf(v.z); l.z = f2bf(v.z - bf2f(h.z));
  h.w = f2bf(v.w); l.w = f2bf(v.w - bf2f(h.w));
  *(ushort4*)(hi + i4) = h;
  *(ushort4*)(lo + i4) = l;
}

__global__ __launch_bounds__(256) void k_cast_w(
    const float* __restrict__ w, unsigned short* __restrict__ wb) {
  const size_t i4 = ((size_t)blockIdx.x * 256 + threadIdx.x) * 4;
  const float4 v = *(const float4*)(w + i4);
  ushort4 h;
  h.x = f2bf(v.x); h.y = f2bf(v.y); h.z = f2bf(v.z); h.w = f2bf(v.w);
  *(ushort4*)(wb + i4) = h;
}

// ---------------------------------------------------------------------------
// QKV GEMM via MFMA, 2-product split-bf16 A (x = hi + lo), bf16 B.
// C[m][n] = sum_k (xhi+xlo)[m][k] * w[n][k] + bias[n]; scatter to q/k/v f32.
// 128x128 tile, BK=64, 4 waves x (4x4) 16x16x32 mfma.
// ---------------------------------------------------------------------------
__global__ __launch_bounds__(256) void k_qkv_mfma(
    const unsigned short* __restrict__ xhi, const unsigned short* __restrict__ xlo,
    const unsigned short* __restrict__ wb, const float* __restrict__ bias,
    float* __restrict__ qb, float* __restrict__ kb, float* __restrict__ vb) {
  __shared__ __align__(16) unsigned short Ah[128 * LDSA];
  __shared__ __align__(16) unsigned short Al[128 * LDSA];
  __shared__ __align__(16) unsigned short Bs[128 * LDSA];
  const int bt0 = blockIdx.x * 128, j0 = blockIdx.y * 128;
  const int tid = threadIdx.x;
  const int lane = tid & 63, wave = tid >> 6;
  const int wm = (wave & 1) * 64, wn = (wave >> 1) * 64;
  const int col = lane & 15, quad = lane >> 4;
  f32x4 acc[4][4] = {};
  const int sr = tid >> 3, sg = tid & 7;  // staging: 32 rows / 8 granules per iter

  for (int k0 = 0; k0 < E_; k0 += 64) {
    __syncthreads();
#pragma unroll
    for (int it = 0; it < 4; ++it) {
      const int r = it * 32 + sr;
      const size_t ga = (size_t)(bt0 + r) * E_ + k0 + sg * 8;
      *(v8s*)&Ah[r * LDSA + sg * 8] = *(const v8s*)(xhi + ga);
      *(v8s*)&Al[r * LDSA + sg * 8] = *(const v8s*)(xlo + ga);
      *(v8s*)&Bs[r * LDSA + sg * 8] =
          *(const v8s*)(wb + (size_t)(j0 + r) * E_ + k0 + sg * 8);
    }
    __syncthreads();
#pragma unroll
    for (int kk = 0; kk < 2; ++kk) {
      v8s ah[4], al[4], bfr[4];
#pragma unroll
      for (int i = 0; i < 4; ++i) {
        const int mo = (wm + i * 16 + col) * LDSA + kk * 32 + quad * 8;
        ah[i] = *(const v8s*)&Ah[mo];
        al[i] = *(const v8s*)&Al[mo];
        bfr[i] = *(const v8s*)&Bs[(wn + i * 16 + col) * LDSA + kk * 32 + quad * 8];
      }
#pragma unroll
      for (int i = 0; i < 4; ++i)
#pragma unroll
        for (int j = 0; j < 4; ++j) {
          acc[i][j] = __builtin_amdgcn_mfma_f32_16x16x32_bf16(ah[i], bfr[j], acc[i][j], 0, 0, 0);
          acc[i][j] = __builtin_amdgcn_mfma_f32_16x16x32_bf16(al[i], bfr[j], acc[i][j], 0, 0, 0);
        }
    }
  }
  // epilogue: C/D layout col=lane&15, row=quad*4+reg
#pragma unroll
  for (int j = 0; j < 4; ++j) {
    const int n = j0 + wn + j * 16 + col;
    const int sec = n >> 10, nn = n & 1023, h = nn >> 6, dd = nn & 63;
    float* dst = (sec == 0) ? qb : ((sec == 1) ? kb : vb);
    const float bv = bias[n];
#pragma unroll
    for (int i = 0; i < 4; ++i) {
      const int mbase = bt0 + wm + i * 16 + quad * 4;
#pragma unroll
      for (int r = 0; r < 4; ++r) {
        const int m = mbase + r;
        const int b = m >> 12, t = m & (T_ - 1);
        dst[((size_t)(b * H_ + h) * T_ + t) * D_ + dd] = acc[i][j][r] + bv;
      }
    }
  }
}

// ---------------------------------------------------------------------------
// Out GEMM via MFMA, plain bf16: out[m][n] = sum_k o[m][k]*w[n][k] + bias[n]
// ---------------------------------------------------------------------------
__global__ __launch_bounds__(256) void k_out_mfma(
    const unsigned short* __restrict__ ob, const unsigned short* __restrict__ wb,
    const float* __restrict__ bias, float* __restrict__ out) {
  __shared__ __align__(16) unsigned short As[128 * LDSA];
  __shared__ __align__(16) unsigned short Bs[128 * LDSA];
  const int bt0 = blockIdx.x * 128, j0 = blockIdx.y * 128;
  const int tid = threadIdx.x;
  const int lane = tid & 63, wave = tid >> 6;
  const int wm = (wave & 1) * 64, wn = (wave >> 1) * 64;
  const int col = lane & 15, quad = lane >> 4;
  f32x4 acc[4][4] = {};
  const int sr = tid >> 3, sg = tid & 7;

  for (int k0 = 0; k0 < E_; k0 += 64) {
    __syncthreads();
#pragma unroll
    for (int it = 0; it < 4; ++it) {
      const int r = it * 32 + sr;
      *(v8s*)&As[r * LDSA + sg * 8] =
          *(const v8s*)(ob + (size_t)(bt0 + r) * E_ + k0 + sg * 8);
      *(v8s*)&Bs[r * LDSA + sg * 8] =
          *(const v8s*)(wb + (size_t)(j0 + r) * E_ + k0 + sg * 8);
    }
    __syncthreads();
#pragma unroll
    for (int kk = 0; kk < 2; ++kk) {
      v8s af[4], bfr[4];
#pragma unroll
      for (int i = 0; i < 4; ++i) {
        af[i] = *(const v8s*)&As[(wm + i * 16 + col) * LDSA + kk * 32 + quad * 8];
        bfr[i] = *(const v8s*)&Bs[(wn + i * 16 + col) * LDSA + kk * 32 + quad * 8];
      }
#pragma unroll
      for (int i = 0; i < 4; ++i)
#pragma unroll
        for (int j = 0; j < 4; ++j)
          acc[i][j] = __builtin_amdgcn_mfma_f32_16x16x32_bf16(af[i], bfr[j], acc[i][j], 0, 0, 0);
    }
  }
#pragma unroll
  for (int j = 0; j < 4; ++j) {
    const int n = j0 + wn + j * 16 + col;
    const float bv = bias[n];
#pragma unroll
    for (int i = 0; i < 4; ++i) {
      const int mbase = bt0 + wm + i * 16 + quad * 4;
#pragma unroll
      for (int r = 0; r < 4; ++r)
        out[(size_t)(mbase + r) * E_ + n] = acc[i][j][r] + bv;
    }
  }
}

// ---------------------------------------------------------------------------
// Features: l2norm rows, then poly[t][p] = (xn.pw)^2/8, prf[t][m] = exp(..)*scale.
// ---------------------------------------------------------------------------
__global__ __launch_bounds__(256) void k_feat(
    const float* xin, const float* __restrict__ poly_w,
    const float* __restrict__ omega, const float* __restrict__ qnod,
    const float* __restrict__ qwt, float* poly_out, float* __restrict__ prf_out) {
  __shared__ float xs[64][65];
  __shared__ float pw[64][64];
  __shared__ float om[64][8];
  const int blk = blockIdx.x;
  const int bh = blk >> 6;
  const int t0 = (blk & 63) * 64;
  const int h = bh & (H_ - 1);
  const int tid = threadIdx.x;
  const int lr = tid >> 4, lc = (tid & 15) << 2;
#pragma unroll
  for (int rr = 0; rr < 64; rr += 16) {
    float4 v = *(const float4*)(xin + ((size_t)bh * T_ + t0 + rr + lr) * D_ + lc);
    xs[rr + lr][lc + 0] = v.x; xs[rr + lr][lc + 1] = v.y;
    xs[rr + lr][lc + 2] = v.z; xs[rr + lr][lc + 3] = v.w;
    *(float4*)(&pw[rr + lr][lc]) =
        *(const float4*)(poly_w + (size_t)h * D_ * P_ + (size_t)(rr + lr) * P_ + lc);
  }
  if (tid < 128) {
    *(float4*)(&om[tid >> 1][(tid & 1) * 4]) =
        *(const float4*)(omega + (size_t)h * D_ * M_ + (size_t)(tid >> 1) * M_ + (tid & 1) * 4);
  }
  __syncthreads();
  const int wv = tid >> 6, lane = tid & 63;
  for (int tt = wv * 16; tt < wv * 16 + 16; ++tt) {
    float xv = xs[tt][lane];
    float ssum = xv * xv;
#pragma unroll
    for (int off = 32; off > 0; off >>= 1) ssum += __shfl_xor(ssum, off);
    const float rn = 1.0f / fmaxf(sqrtf(ssum), 1e-12f);
    xs[tt][lane] = xv * rn;
  }
  __syncthreads();
  const int p = tid & 63, tg = tid >> 6;
  for (int k = 0; k < 16; ++k) {
    const int t = tg * 16 + k;
    float a = 0.f;
#pragma unroll
    for (int d = 0; d < 64; ++d) a += xs[t][d] * pw[d][p];
    poly_out[((size_t)bh * T_ + t0 + t) * P_ + p] = a * a * 0.125f;
  }
  const float s0 = qnod[0];
  const float sq2 = sqrtf(fmaxf(2.f * s0, 0.f));
  const float scale = sqrtf(fmaxf(qwt[0], 0.f)) * 0.3535533905932738f;
  const int m = tid & 7, tq = tid >> 3;
#pragma unroll
  for (int rep = 0; rep < 2; ++rep) {
    const int t = tq + rep * 32;
    float a = 0.f;
#pragma unroll
    for (int d = 0; d < 64; ++d) a += xs[t][d] * om[d][m];
    float z = fminf(fmaxf(a * sq2 - s0, -20.f), 20.f);
    prf_out[((size_t)bh * T_ + t0 + t) * M_ + m] = expf(z) * scale;
  }
}

// ---------------------------------------------------------------------------
// Phase A: per (c,bh): kv_c[d][pm] = sum_t kf[t,pm]*v[t,d] (bf16 out);
// ksum_c[pm] = sum_t kf (f32).
// ---------------------------------------------------------------------------
__global__ __launch_bounds__(512) void k_phaseA(
    const float* __restrict__ polyk, const float* __restrict__ prfk,
    const float* __restrict__ vbuf, unsigned short* __restrict__ kvch,
    float* __restrict__ ksum) {
  __shared__ float pk[64][64];
  __shared__ float vs[64][64];
  const int bh = blockIdx.x & (BH_ - 1);
  const int c = blockIdx.x >> 5;
  const int tid = threadIdx.x;
  const int lr = tid >> 4, lc = (tid & 15) << 2;
  const int pm = tid, p = pm >> 3, m = pm & 7;
  const float* fkg = prfk + ((size_t)bh * T_ + (size_t)c * CH_) * M_ + m;
  float acc[64];
#pragma unroll
  for (int d = 0; d < 64; ++d) acc[d] = 0.f;
  float ks = 0.f;
  for (int half = 0; half < 2; ++half) {
    __syncthreads();
#pragma unroll
    for (int rr = 0; rr < 64; rr += 32) {
      const int r = rr + lr;
      *(float4*)(&pk[r][lc]) =
          *(const float4*)(polyk + ((size_t)bh * T_ + c * CH_ + half * 64 + r) * P_ + lc);
      *(float4*)(&vs[r][lc]) =
          *(const float4*)(vbuf + ((size_t)bh * T_ + c * CH_ + half * 64 + r) * D_ + lc);
    }
    __syncthreads();
    for (int t = 0; t < 64; ++t) {
      const float kf = pk[t][p] * fkg[(size_t)(half * 64 + t) * M_];
      ks += kf;
#pragma unroll
      for (int j = 0; j < 16; ++j) {
        const float4 v4 = *(const float4*)(&vs[t][j * 4]);
        acc[j * 4 + 0] += kf * v4.x; acc[j * 4 + 1] += kf * v4.y;
        acc[j * 4 + 2] += kf * v4.z; acc[j * 4 + 3] += kf * v4.w;
      }
    }
  }
  const size_t base = (size_t)(c * BH_ + bh) * D_ * F_;
#pragma unroll
  for (int d = 0; d < 64; ++d) kvch[base + (size_t)d * F_ + pm] = f2bf(acc[d]);
  ksum[(size_t)(c * BH_ + bh) * F_ + pm] = ks;
}

// ---------------------------------------------------------------------------
// Exclusive prefix over chunks, in place.
// ---------------------------------------------------------------------------
__global__ __launch_bounds__(256) void k_scan_kv(unsigned short* __restrict__ kvch) {
  const size_t s = (size_t)blockIdx.x * 256 + threadIdx.x;
  const size_t stride = (size_t)BH_ * D_ * F_;
  unsigned short v[NC_];
#pragma unroll
  for (int c = 0; c < NC_; ++c) v[c] = kvch[(size_t)c * stride + s];
  float run = 0.f;
#pragma unroll
  for (int c = 0; c < NC_; ++c) {
    const float t = bf2f(v[c]);
    kvch[(size_t)c * stride + s] = f2bf(run);
    run += t;
  }
}

__global__ __launch_bounds__(256) void k_scan_ks(float* __restrict__ ksum) {
  const int s = blockIdx.x * 256 + threadIdx.x;
  const int stride = BH_ * F_;
  float v[NC_];
#pragma unroll
  for (int c = 0; c < NC_; ++c) v[c] = ksum[c * stride + s];
  float run = 0.f;
#pragma unroll
  for (int c = 0; c < NC_; ++c) {
    const float t = v[c];
    ksum[c * stride + s] = run;
    run += t;
  }
}

// ---------------------------------------------------------------------------
// Fused scores+intra (unchanged from round 2)
// ---------------------------------------------------------------------------
__global__ __launch_bounds__(256) void k_sintra(
    const float* __restrict__ polyq, const float* __restrict__ prfq,
    const float* __restrict__ polyk, const float* __restrict__ prfk,
    const float* __restrict__ vbuf, float* __restrict__ obuf,
    float* __restrict__ nrmbuf) {
  __shared__ float pq[CH_][65];
  __shared__ float fq[CH_][8];
  __shared__ float pk[16][65];
  __shared__ float fk[16][8];
  __shared__ float vsl[16][64];
  __shared__ float ss[CH_][17];
  const int bh = blockIdx.x & (BH_ - 1);
  const int c = blockIdx.x >> 5;
  const int tid = threadIdx.x;
  const size_t rowQ = (size_t)bh * T_ + (size_t)c * CH_;
  const int lr = tid >> 4, lc = (tid & 15) << 2;
#pragma unroll
  for (int rr = 0; rr < CH_; rr += 16) {
    float4 v = *(const float4*)(polyq + (rowQ + rr + lr) * P_ + lc);
    pq[rr + lr][lc + 0] = v.x; pq[rr + lr][lc + 1] = v.y;
    pq[rr + lr][lc + 2] = v.z; pq[rr + lr][lc + 3] = v.w;
  }
  *(float4*)(&fq[tid >> 1][(tid & 1) * 4]) =
      *(const float4*)(prfq + (rowQ + (tid >> 1)) * M_ + (tid & 1) * 4);

  float acc[32], rs[32];
#pragma unroll
  for (int k = 0; k < 32; ++k) { acc[k] = 0.f; rs[k] = 0.f; }
  const int s16 = tid & 15, tg16 = tid >> 4;
  const int d = tid & 63, tg4 = tid >> 6;

  for (int st = 0; st < 8; ++st) {
    __syncthreads();
    {
      const int r = tid >> 4, c4 = (tid & 15) << 2;
      float4 a = *(const float4*)(polyk + (rowQ + st * 16 + r) * P_ + c4);
      pk[r][c4 + 0] = a.x; pk[r][c4 + 1] = a.y;
      pk[r][c4 + 2] = a.z; pk[r][c4 + 3] = a.w;
      *(float4*)(&vsl[r][c4]) =
          *(const float4*)(vbuf + (rowQ + st * 16 + r) * D_ + c4);
      if (tid < 32) {
        *(float4*)(&fk[tid >> 1][(tid & 1) * 4]) =
            *(const float4*)(prfk + (rowQ + st * 16 + (tid >> 1)) * M_ + (tid & 1) * 4);
      }
    }
    __syncthreads();
    {
      float pkr[64];
#pragma unroll
      for (int p2 = 0; p2 < 64; ++p2) pkr[p2] = pk[s16][p2];
      const float f0 = fk[s16][0], f1 = fk[s16][1], f2 = fk[s16][2], f3 = fk[s16][3];
      const float f4 = fk[s16][4], f5 = fk[s16][5], f6 = fk[s16][6], f7 = fk[s16][7];
      const int sg2 = st * 16 + s16;
#pragma unroll
      for (int r = 0; r < 8; ++r) {
        const int t = tg16 * 8 + r;
        float aP = 0.f;
#pragma unroll
        for (int p2 = 0; p2 < 64; ++p2) aP += pq[t][p2] * pkr[p2];
        const float aM = fq[t][0] * f0 + fq[t][1] * f1 + fq[t][2] * f2 + fq[t][3] * f3 +
                         fq[t][4] * f4 + fq[t][5] * f5 + fq[t][6] * f6 + fq[t][7] * f7;
        ss[t][s16] = (sg2 <= t) ? aP * aM : 0.f;
      }
    }
    __syncthreads();
    for (int sj = 0; sj < 16; ++sj) {
      const float vd = vsl[sj][d];
#pragma unroll
      for (int k = 0; k < 32; ++k) {
        const float sv = ss[(k << 2) | tg4][sj];
        acc[k] += sv * vd;
        rs[k] += sv;
      }
    }
  }
  const size_t nbase = (size_t)(c * BH_ + bh) * CH_;
#pragma unroll
  for (int k = 0; k < 32; ++k) {
    const int t = (k << 2) | tg4;
    obuf[(rowQ + t) * D_ + d] = acc[k];
    if (d == 0) nrmbuf[nbase + t] = rs[k];
  }
}

// ---------------------------------------------------------------------------
// Hist + finalize: o = (ci+ch)/(nh+rowsum+DELTA), written as bf16 in (bt, e)
// GEMM-ready layout for k_out_mfma.
// ---------------------------------------------------------------------------
__global__ __launch_bounds__(256) void k_hist(
    const float* __restrict__ polyq, const float* __restrict__ prfq,
    const unsigned short* __restrict__ kvch, const float* __restrict__ ksum,
    const float* __restrict__ nrmbuf, const float* __restrict__ obuf,
    unsigned short* __restrict__ obf) {
  __shared__ float pq[CH_][64];
  __shared__ float fq[CH_][8];
  __shared__ float kvt[64][65];
  __shared__ float kp[F_];
  __shared__ float nhs[CH_];
  const int bh = blockIdx.x & (BH_ - 1);
  const int c = blockIdx.x >> 5;
  const int b = bh >> 4, h = bh & (H_ - 1);
  const int tid = threadIdx.x;
  const int lr = tid >> 4, lc = (tid & 15) << 2;
#pragma unroll
  for (int rr = 0; rr < CH_; rr += 16)
    *(float4*)(&pq[rr + lr][lc]) =
        *(const float4*)(polyq + ((size_t)bh * T_ + c * CH_ + rr + lr) * P_ + lc);
  *(float4*)(&fq[tid >> 1][(tid & 1) * 4]) =
      *(const float4*)(prfq + ((size_t)bh * T_ + c * CH_ + (tid >> 1)) * M_ + (tid & 1) * 4);
  if (tid < 128)
    *(float4*)(&kp[tid * 4]) =
        *(const float4*)(ksum + (size_t)(c * BH_ + bh) * F_ + tid * 4);
  __syncthreads();
  if (tid < CH_) {
    const int t = tid;
    float fr[8];
#pragma unroll
    for (int mm = 0; mm < 8; ++mm) fr[mm] = fq[t][mm];
    float nh = 0.f;
#pragma unroll
    for (int p2 = 0; p2 < 64; ++p2) {
      float tmp = 0.f;
#pragma unroll
      for (int mm = 0; mm < 8; ++mm) tmp += fr[mm] * kp[p2 * 8 + mm];
      nh += pq[t][p2] * tmp;
    }
    nhs[t] = nh;
  }
  const int d = tid & 63, tg = tid >> 6;
  float ch[32];
#pragma unroll
  for (int k = 0; k < 32; ++k) ch[k] = 0.f;
  const size_t kvbase = (size_t)(c * BH_ + bh) * D_ * F_;
  for (int pmt = 0; pmt < 8; ++pmt) {
    __syncthreads();
#pragma unroll
    for (int rr = 0; rr < 64; rr += 16) {
      const ushort4 u = *(const ushort4*)(kvch + kvbase + (size_t)(rr + lr) * F_ + pmt * 64 + lc);
      kvt[rr + lr][lc + 0] = bf2f(u.x); kvt[rr + lr][lc + 1] = bf2f(u.y);
      kvt[rr + lr][lc + 2] = bf2f(u.z); kvt[rr + lr][lc + 3] = bf2f(u.w);
    }
    __syncthreads();
#pragma unroll
    for (int k = 0; k < 32; ++k) {
      const int t = tg * 32 + k;
      const float f0 = fq[t][0], f1 = fq[t][1], f2 = fq[t][2], f3 = fq[t][3];
      const float f4 = fq[t][4], f5 = fq[t][5], f6 = fq[t][6], f7 = fq[t][7];
      float a = 0.f;
#pragma unroll
      for (int pl = 0; pl < 8; ++pl) {
        const int pb = pl * 8;
        float tmp = f0 * kvt[d][pb + 0] + f1 * kvt[d][pb + 1] +
                    f2 * kvt[d][pb + 2] + f3 * kvt[d][pb + 3] +
                    f4 * kvt[d][pb + 4] + f5 * kvt[d][pb + 5] +
                    f6 * kvt[d][pb + 6] + f7 * kvt[d][pb + 7];
        a += pq[t][pmt * 8 + pl] * tmp;
      }
      ch[k] += a;
    }
  }
  const size_t obase = ((size_t)bh * T_ + c * CH_) * D_;
  const size_t nbase = (size_t)(c * BH_ + bh) * CH_;
#pragma unroll
  for (int k = 0; k < 32; ++k) {
    const int t = tg * 32 + k;
    const float nrm = nhs[t] + nrmbuf[nbase + t] + 1e-6f;
    const float val = (obuf[obase + (size_t)t * D_ + d] + ch[k]) / nrm;
    obf[(size_t)(b * T_ + c * CH_ + t) * E_ + h * 64 + d] = f2bf(val);
  }
}

// ---------------------------------------------------------------------------
extern "C" void kernel_launch(void* const* d_in, const int* in_sizes, int n_in,
                              void* d_out, int out_size, void* d_ws, size_t ws_size,
                              hipStream_t stream) {
  (void)in_sizes; (void)n_in; (void)out_size; (void)ws_size;
  const float* x      = (const float*)d_in[0];
  const float* qkv_w  = (const float*)d_in[1];
  const float* qkv_b  = (const float*)d_in[2];
  const float* out_w  = (const float*)d_in[3];
  const float* out_b  = (const float*)d_in[4];
  const float* omega  = (const float*)d_in[5];
  const float* poly_w = (const float*)d_in[6];
  const float* qnod   = (const float*)d_in[7];
  const float* qwt    = (const float*)d_in[8];
  float* ws = (float*)d_ws;
  float* qb   = ws + OFF_Q;
  float* kb   = ws + OFF_K;
  float* vb   = ws + OFF_V;
  float* fqb  = ws + OFF_FQ;
  float* fkb  = ws + OFF_FK;
  float* ksb  = ws + OFF_KS;
  float* nrmb = ws + OFF_NRM;
  float* ob   = ws + OFF_O;
  unsigned short* kvb = (unsigned short*)(ws + OFF_KV);
  // pre-qkv overlays inside the kv region (dead once k_qkv_mfma completes):
  unsigned short* xhi  = kvb;                     // 16.8 MB
  unsigned short* xlo  = kvb + SZ_BHTD;           // 16.8 MB
  unsigned short* wqkv = kvb + 2 * SZ_BHTD;       //  6.3 MB  (<= 67 MB region)
  // post-sintra overlays:
  unsigned short* obf   = (unsigned short*)kb;    // o bf16 (bt,e), over polyk
  unsigned short* woutb = (unsigned short*)vb;    // out_w bf16, over v
  float* outp = (float*)d_out;

  hipLaunchKernelGGL(k_split_x, dim3(8192), dim3(256), 0, stream, x, xhi, xlo);
  hipLaunchKernelGGL(k_cast_w, dim3(3072), dim3(256), 0, stream, qkv_w, wqkv);
  hipLaunchKernelGGL(k_qkv_mfma, dim3(BT_ / 128, 3 * E_ / 128), dim3(256), 0, stream,
                     xhi, xlo, wqkv, qkv_b, qb, kb, vb);
  hipLaunchKernelGGL(k_feat, dim3(2048), dim3(256), 0, stream,
                     qb, poly_w, omega, qnod, qwt, qb, fqb);
  hipLaunchKernelGGL(k_feat, dim3(2048), dim3(256), 0, stream,
                     kb, poly_w, omega, qnod, qwt, kb, fkb);
  hipLaunchKernelGGL(k_phaseA, dim3(NC_ * BH_), dim3(512), 0, stream,
                     kb, fkb, vb, kvb, ksb);
  hipLaunchKernelGGL(k_scan_kv, dim3(4096), dim3(256), 0, stream, kvb);
  hipLaunchKernelGGL(k_scan_ks, dim3(64), dim3(256), 0, stream, ksb);
  hipLaunchKernelGGL(k_sintra, dim3(NC_ * BH_), dim3(256), 0, stream,
                     qb, fqb, kb, fkb, vb, ob, nrmb);
  hipLaunchKernelGGL(k_cast_w, dim3(1024), dim3(256), 0, stream, out_w, woutb);
  hipLaunchKernelGGL(k_hist, dim3(NC_ * BH_), dim3(256), 0, stream,
                     qb, fqb, kvb, ksb, nrmb, ob, obf);
  hipLaunchKernelGGL(k_out_mfma, dim3(BT_ / 128, E_ / 128), dim3(256), 0, stream,
                     obf, woutb, out_b, outp);
}

// Round 4
// 761.091 us; speedup vs baseline: 2.6509x; 1.2054x over previous
//
#include <hip/hip_runtime.h>
#include <math.h>

#define B_ 2
#define T_ 4096
#define E_ 1024
#define H_ 16
#define D_ 64
#define P_ 64
#define M_ 8
#define CH_ 256
#define NC_ 16
#define F_ 512
#define BH_ 32
#define BT_ 8192

// ---- workspace layout ----
static constexpr size_t SZ_BHTD = (size_t)B_ * H_ * T_ * D_;     // 8,388,608
static constexpr size_t SZ_PRF  = (size_t)B_ * H_ * T_ * M_;     // 1,048,576 (region in f32 units; holds bf16)
static constexpr size_t SZ_KS   = (size_t)NC_ * BH_ * F_;        // 262,144
static constexpr size_t SZ_NRM  = (size_t)NC_ * BH_ * CH_;       // 131,072
static constexpr size_t SZ_KV_E = 33554432;                      // bf16 region: kv | polyq_bf | polyk_bf

static constexpr size_t OFF_Q   = 0;                  // raw q f32 (dead after feat)
static constexpr size_t OFF_K   = OFF_Q + SZ_BHTD;    // raw k f32; obf overlay post-feat
static constexpr size_t OFF_V   = OFF_K + SZ_BHTD;    // v f32; woutb overlay post-sintra/phaseA
static constexpr size_t OFF_FQ  = OFF_V + SZ_BHTD;    // prfq bf16 (half of region used)
static constexpr size_t OFF_FK  = OFF_FQ + SZ_PRF;    // prfk bf16
static constexpr size_t OFF_KS  = OFF_FK + SZ_PRF;
static constexpr size_t OFF_NRM = OFF_KS + SZ_KS;
static constexpr size_t OFF_O   = OFF_NRM + SZ_NRM;   // intra ctx f32
static constexpr size_t OFF_KV  = OFF_O + SZ_BHTD;    // bf16: [kv 16.78M | polyq 8.39M | polyk 8.39M]
// total = OFF_KV*4 + SZ_KV_E*2 = 211,288,064 B (~201.5 MiB) <= round-3's proven 202.5 MiB

__device__ __forceinline__ float bf2f(unsigned short u) {
  union { unsigned u32; float f; } x; x.u32 = ((unsigned)u) << 16; return x.f;
}
__device__ __forceinline__ unsigned short f2bf(float f) {
  union { float f; unsigned u; } x; x.f = f;
  unsigned r = x.u + 0x7fffu + ((x.u >> 16) & 1u);
  return (unsigned short)(r >> 16);
}

typedef short v8s __attribute__((ext_vector_type(8)));
typedef unsigned short u16x8 __attribute__((ext_vector_type(8)));
typedef float f32x4 __attribute__((ext_vector_type(4)));
#define LDSA 72   // GEMM LDS stride (bf16)

// ---------------------------------------------------------------------------
__global__ __launch_bounds__(256) void k_split_x(
    const float* __restrict__ x, unsigned short* __restrict__ hi,
    unsigned short* __restrict__ lo) {
  const size_t i4 = ((size_t)blockIdx.x * 256 + threadIdx.x) * 4;
  const float4 v = *(const float4*)(x + i4);
  ushort4 h, l;
  h.x = f2bf(v.x); l.x = f2bf(v.x - bf2f(h.x));
  h.y = f2bf(v.y); l.y = f2bf(v.y - bf2f(h.y));
  h.z = f2bf(v.z); l.z = f2bf(v.z - bf2f(h.z));
  h.w = f2bf(v.w); l.w = f2bf(v.w - bf2f(h.w));
  *(ushort4*)(hi + i4) = h;
  *(ushort4*)(lo + i4) = l;
}

__global__ __launch_bounds__(256) void k_cast_w(
    const float* __restrict__ w, unsigned short* __restrict__ wb) {
  const size_t i4 = ((size_t)blockIdx.x * 256 + threadIdx.x) * 4;
  const float4 v = *(const float4*)(w + i4);
  ushort4 h;
  h.x = f2bf(v.x); h.y = f2bf(v.y); h.z = f2bf(v.z); h.w = f2bf(v.w);
  *(ushort4*)(wb + i4) = h;
}

// ---------------------------------------------------------------------------
// QKV GEMM via MFMA, split-bf16 A, bf16 B. (unchanged from round 3)
// ---------------------------------------------------------------------------
__global__ __launch_bounds__(256) void k_qkv_mfma(
    const unsigned short* __restrict__ xhi, const unsigned short* __restrict__ xlo,
    const unsigned short* __restrict__ wb, const float* __restrict__ bias,
    float* __restrict__ qb, float* __restrict__ kb, float* __restrict__ vb) {
  __shared__ __align__(16) unsigned short Ah[128 * LDSA];
  __shared__ __align__(16) unsigned short Al[128 * LDSA];
  __shared__ __align__(16) unsigned short Bs[128 * LDSA];
  const int bt0 = blockIdx.x * 128, j0 = blockIdx.y * 128;
  const int tid = threadIdx.x;
  const int lane = tid & 63, wave = tid >> 6;
  const int wm = (wave & 1) * 64, wn = (wave >> 1) * 64;
  const int col = lane & 15, quad = lane >> 4;
  f32x4 acc[4][4] = {};
  const int sr = tid >> 3, sg = tid & 7;

  for (int k0 = 0; k0 < E_; k0 += 64) {
    __syncthreads();
#pragma unroll
    for (int it = 0; it < 4; ++it) {
      const int r = it * 32 + sr;
      const size_t ga = (size_t)(bt0 + r) * E_ + k0 + sg * 8;
      *(v8s*)&Ah[r * LDSA + sg * 8] = *(const v8s*)(xhi + ga);
      *(v8s*)&Al[r * LDSA + sg * 8] = *(const v8s*)(xlo + ga);
      *(v8s*)&Bs[r * LDSA + sg * 8] =
          *(const v8s*)(wb + (size_t)(j0 + r) * E_ + k0 + sg * 8);
    }
    __syncthreads();
#pragma unroll
    for (int kk = 0; kk < 2; ++kk) {
      v8s ah[4], al[4], bfr[4];
#pragma unroll
      for (int i = 0; i < 4; ++i) {
        const int mo = (wm + i * 16 + col) * LDSA + kk * 32 + quad * 8;
        ah[i] = *(const v8s*)&Ah[mo];
        al[i] = *(const v8s*)&Al[mo];
        bfr[i] = *(const v8s*)&Bs[(wn + i * 16 + col) * LDSA + kk * 32 + quad * 8];
      }
#pragma unroll
      for (int i = 0; i < 4; ++i)
#pragma unroll
        for (int j = 0; j < 4; ++j) {
          acc[i][j] = __builtin_amdgcn_mfma_f32_16x16x32_bf16(ah[i], bfr[j], acc[i][j], 0, 0, 0);
          acc[i][j] = __builtin_amdgcn_mfma_f32_16x16x32_bf16(al[i], bfr[j], acc[i][j], 0, 0, 0);
        }
    }
  }
#pragma unroll
  for (int j = 0; j < 4; ++j) {
    const int n = j0 + wn + j * 16 + col;
    const int sec = n >> 10, nn = n & 1023, h = nn >> 6, dd = nn & 63;
    float* dst = (sec == 0) ? qb : ((sec == 1) ? kb : vb);
    const float bv = bias[n];
#pragma unroll
    for (int i = 0; i < 4; ++i) {
      const int mbase = bt0 + wm + i * 16 + quad * 4;
#pragma unroll
      for (int r = 0; r < 4; ++r) {
        const int m = mbase + r;
        const int b = m >> 12, t = m & (T_ - 1);
        dst[((size_t)(b * H_ + h) * T_ + t) * D_ + dd] = acc[i][j][r] + bv;
      }
    }
  }
}

// ---------------------------------------------------------------------------
// Features: l2norm, poly -> bf16, prf -> bf16.
// ---------------------------------------------------------------------------
__global__ __launch_bounds__(256) void k_feat(
    const float* __restrict__ xin, const float* __restrict__ poly_w,
    const float* __restrict__ omega, const float* __restrict__ qnod,
    const float* __restrict__ qwt, unsigned short* __restrict__ poly_bf,
    unsigned short* __restrict__ prf_bf) {
  __shared__ float xs[64][65];
  __shared__ float pw[64][64];
  __shared__ float om[64][8];
  const int blk = blockIdx.x;
  const int bh = blk >> 6;
  const int t0 = (blk & 63) * 64;
  const int h = bh & (H_ - 1);
  const int tid = threadIdx.x;
  const int lr = tid >> 4, lc = (tid & 15) << 2;
#pragma unroll
  for (int rr = 0; rr < 64; rr += 16) {
    float4 v = *(const float4*)(xin + ((size_t)bh * T_ + t0 + rr + lr) * D_ + lc);
    xs[rr + lr][lc + 0] = v.x; xs[rr + lr][lc + 1] = v.y;
    xs[rr + lr][lc + 2] = v.z; xs[rr + lr][lc + 3] = v.w;
    *(float4*)(&pw[rr + lr][lc]) =
        *(const float4*)(poly_w + (size_t)h * D_ * P_ + (size_t)(rr + lr) * P_ + lc);
  }
  if (tid < 128) {
    *(float4*)(&om[tid >> 1][(tid & 1) * 4]) =
        *(const float4*)(omega + (size_t)h * D_ * M_ + (size_t)(tid >> 1) * M_ + (tid & 1) * 4);
  }
  __syncthreads();
  const int wv = tid >> 6, lane = tid & 63;
  for (int tt = wv * 16; tt < wv * 16 + 16; ++tt) {
    float xv = xs[tt][lane];
    float ssum = xv * xv;
#pragma unroll
    for (int off = 32; off > 0; off >>= 1) ssum += __shfl_xor(ssum, off);
    const float rn = 1.0f / fmaxf(sqrtf(ssum), 1e-12f);
    xs[tt][lane] = xv * rn;
  }
  __syncthreads();
  const int p = tid & 63, tg = tid >> 6;
  for (int k = 0; k < 16; ++k) {
    const int t = tg * 16 + k;
    float a = 0.f;
#pragma unroll
    for (int d = 0; d < 64; ++d) a += xs[t][d] * pw[d][p];
    poly_bf[((size_t)bh * T_ + t0 + t) * P_ + p] = f2bf(a * a * 0.125f);
  }
  const float s0 = qnod[0];
  const float sq2 = sqrtf(fmaxf(2.f * s0, 0.f));
  const float scale = sqrtf(fmaxf(qwt[0], 0.f)) * 0.3535533905932738f;
  const int m = tid & 7, tq = tid >> 3;
#pragma unroll
  for (int rep = 0; rep < 2; ++rep) {
    const int t = tq + rep * 32;
    float a = 0.f;
#pragma unroll
    for (int d = 0; d < 64; ++d) a += xs[t][d] * om[d][m];
    float z = fminf(fmaxf(a * sq2 - s0, -20.f), 20.f);
    prf_bf[((size_t)bh * T_ + t0 + t) * M_ + m] = f2bf(expf(z) * scale);
  }
}

// ---------------------------------------------------------------------------
// Phase A (CH=256): kv_c[d][pm] = sum_t kf[t,pm]*v[t,d]; ksum_c[pm] = sum_t kf.
// poly/prf inputs bf16, staged to f32 LDS. 4 passes of 64 rows.
// ---------------------------------------------------------------------------
__global__ __launch_bounds__(512) void k_phaseA(
    const unsigned short* __restrict__ polyk, const unsigned short* __restrict__ prfk,
    const float* __restrict__ vbuf, unsigned short* __restrict__ kvch,
    float* __restrict__ ksum) {
  __shared__ float pk[64][64];
  __shared__ float vs[64][64];
  const int bh = blockIdx.x & (BH_ - 1);
  const int c = blockIdx.x >> 5;
  const int tid = threadIdx.x;
  const int pm = tid, p = pm >> 3, m = pm & 7;
  const size_t rowC = (size_t)bh * T_ + (size_t)c * CH_;
  float acc[64];
#pragma unroll
  for (int d = 0; d < 64; ++d) acc[d] = 0.f;
  float ks = 0.f;
  const int slr = tid >> 3, sgr = tid & 7;   // 64 rows x 8 granules
  for (int qtr = 0; qtr < 4; ++qtr) {
    __syncthreads();
    {
      const size_t grow = rowC + qtr * 64 + slr;
      v8s pv = *(const v8s*)(polyk + grow * P_ + sgr * 8);
#pragma unroll
      for (int j = 0; j < 8; ++j) pk[slr][sgr * 8 + j] = bf2f((unsigned short)pv[j]);
      *(float4*)(&vs[slr][sgr * 8]) = *(const float4*)(vbuf + grow * D_ + sgr * 8);
      *(float4*)(&vs[slr][sgr * 8 + 4]) = *(const float4*)(vbuf + grow * D_ + sgr * 8 + 4);
    }
    __syncthreads();
    const unsigned short* fkg = prfk + (rowC + qtr * 64) * M_ + m;
    for (int t = 0; t < 64; ++t) {
      const float kf = pk[t][p] * bf2f(fkg[(size_t)t * M_]);
      ks += kf;
#pragma unroll
      for (int j = 0; j < 16; ++j) {
        const float4 v4 = *(const float4*)(&vs[t][j * 4]);
        acc[j * 4 + 0] += kf * v4.x; acc[j * 4 + 1] += kf * v4.y;
        acc[j * 4 + 2] += kf * v4.z; acc[j * 4 + 3] += kf * v4.w;
      }
    }
  }
  const size_t base = (size_t)(c * BH_ + bh) * D_ * F_;
#pragma unroll
  for (int d = 0; d < 64; ++d) kvch[base + (size_t)d * F_ + pm] = f2bf(acc[d]);
  ksum[(size_t)(c * BH_ + bh) * F_ + pm] = ks;
}

// ---------------------------------------------------------------------------
__global__ __launch_bounds__(256) void k_scan_kv(unsigned short* __restrict__ kvch) {
  const size_t s = (size_t)blockIdx.x * 256 + threadIdx.x;
  const size_t stride = (size_t)BH_ * D_ * F_;
  unsigned short v[NC_];
#pragma unroll
  for (int c = 0; c < NC_; ++c) v[c] = kvch[(size_t)c * stride + s];
  float run = 0.f;
#pragma unroll
  for (int c = 0; c < NC_; ++c) {
    const float t = bf2f(v[c]);
    kvch[(size_t)c * stride + s] = f2bf(run);
    run += t;
  }
}

__global__ __launch_bounds__(256) void k_scan_ks(float* __restrict__ ksum) {
  const int s = blockIdx.x * 256 + threadIdx.x;
  const int stride = BH_ * F_;
  float v[NC_];
#pragma unroll
  for (int c = 0; c < NC_; ++c) v[c] = ksum[c * stride + s];
  float run = 0.f;
#pragma unroll
  for (int c = 0; c < NC_; ++c) {
    const float t = v[c];
    ksum[c * stride + s] = run;
    run += t;
  }
}

// ---------------------------------------------------------------------------
// Fused scores+intra via MFMA. Block = (bh, tq128): 1024 blocks, 128 t-rows.
// S^T tiles by mfma(pk,pq) -> packed b64 LDS write; ctx = S@V via mfma(S, VT).
// pq/fq fragments are block-lifetime registers (no LDS). LDS = 55.3 KB.
// ---------------------------------------------------------------------------
__global__ __launch_bounds__(256) void k_sintra(
    const unsigned short* __restrict__ pqb, const unsigned short* __restrict__ fqb,
    const unsigned short* __restrict__ pkb, const unsigned short* __restrict__ fkb,
    const float* __restrict__ vbuf, float* __restrict__ obuf,
    float* __restrict__ nrmbuf) {
  __shared__ __align__(16) unsigned short S_lds[128 * 136];  // [t][s] 34,816 B
  __shared__ __align__(16) unsigned short VT[64 * 136];      // [d][s] 17,408 B
  __shared__ float fk_lds[128][8];                           //  4,096 B
  const int bh = blockIdx.x & (BH_ - 1);
  const int tq = blockIdx.x >> 5;          // 128-tile index in T (0..31)
  const int c = tq >> 1, h2 = tq & 1;
  const size_t rowT = (size_t)bh * T_ + (size_t)tq * 128;
  const size_t rowC = (size_t)bh * T_ + (size_t)c * CH_;
  const int tid = threadIdx.x, lane = tid & 63, w = tid >> 6;
  const int col = lane & 15, quad = lane >> 4;

  // block-lifetime q-side fragments
  v8s bq[2][2];
  float fqr[2][8];
#pragma unroll
  for (int i = 0; i < 2; ++i) {
    const size_t qrow = rowT + (2 * w + i) * 16 + col;
    bq[i][0] = *(const v8s*)(pqb + qrow * P_ + quad * 8);
    bq[i][1] = *(const v8s*)(pqb + qrow * P_ + 32 + quad * 8);
    const v8s fv = *(const v8s*)(fqb + qrow * M_);
#pragma unroll
    for (int j = 0; j < 8; ++j) fqr[i][j] = bf2f((unsigned short)fv[j]);
  }
  f32x4 acc[2][4] = {};
  float rs[2] = {0.f, 0.f};

  const int vd = tid & 63, vg = tid >> 6;  // VT staging split

  for (int sl = 0; sl <= h2; ++sl) {
    const size_t rowS = rowC + (size_t)sl * 128;
    __syncthreads();
    // stage fk (f32) and VT (bf16 transposed V)
    if (tid < 128) {
      const v8s fv = *(const v8s*)(fkb + (rowS + tid) * M_);
#pragma unroll
      for (int j = 0; j < 8; ++j) fk_lds[tid][j] = bf2f((unsigned short)fv[j]);
    }
#pragma unroll
    for (int j8 = 0; j8 < 4; ++j8) {
      const int s0 = vg * 32 + j8 * 8;
      u16x8 pkt;
#pragma unroll
      for (int k = 0; k < 8; ++k)
        pkt[k] = f2bf(vbuf[(rowS + s0 + k) * D_ + vd]);
      *(u16x8*)&VT[vd * 136 + s0] = pkt;
    }
    __syncthreads();
    // SCORE: S^T tiles -> S_lds[t][s] (bf16), rowsum partials in rs[]
#pragma unroll
    for (int i = 0; i < 2; ++i) {
      const int tt = 2 * w + i;
      const int t_rel = h2 * 128 + tt * 16 + col;  // chunk-relative t (lane's C-col)
      for (int si = 0; si < 8; ++si) {
        const size_t ar = rowS + si * 16 + col;
        const v8s a0 = *(const v8s*)(pkb + ar * P_ + quad * 8);
        const v8s a1 = *(const v8s*)(pkb + ar * P_ + 32 + quad * 8);
        f32x4 sp = {};
        sp = __builtin_amdgcn_mfma_f32_16x16x32_bf16(a0, bq[i][0], sp, 0, 0, 0);
        sp = __builtin_amdgcn_mfma_f32_16x16x32_bf16(a1, bq[i][1], sp, 0, 0, 0);
        ushort4 pk4;
        float partial = 0.f;
#pragma unroll
        for (int r = 0; r < 4; ++r) {
          const int s_in = si * 16 + quad * 4 + r;
          const float4 f0 = *(const float4*)&fk_lds[s_in][0];
          const float4 f1 = *(const float4*)&fk_lds[s_in][4];
          const float sm = f0.x * fqr[i][0] + f0.y * fqr[i][1] + f0.z * fqr[i][2] +
                           f0.w * fqr[i][3] + f1.x * fqr[i][4] + f1.y * fqr[i][5] +
                           f1.z * fqr[i][6] + f1.w * fqr[i][7];
          float val = sp[r] * sm;
          const int s_rel = sl * 128 + s_in;
          val = (s_rel <= t_rel) ? val : 0.f;
          partial += val;
          ((unsigned short*)&pk4)[r] = f2bf(val);
        }
        rs[i] += partial;
        *(ushort4*)&S_lds[(tt * 16 + col) * 136 + si * 16 + quad * 4] = pk4;
      }
    }
    __syncthreads();
    // S@V: ctx += S (A) x VT (B)
#pragma unroll
    for (int i = 0; i < 2; ++i) {
      const int tt = 2 * w + i;
#pragma unroll
      for (int kk = 0; kk < 4; ++kk) {
        const v8s sa = *(const v8s*)&S_lds[(tt * 16 + col) * 136 + kk * 32 + quad * 8];
#pragma unroll
        for (int dt = 0; dt < 4; ++dt) {
          const v8s vb8 = *(const v8s*)&VT[(dt * 16 + col) * 136 + kk * 32 + quad * 8];
          acc[i][dt] = __builtin_amdgcn_mfma_f32_16x16x32_bf16(sa, vb8, acc[i][dt], 0, 0, 0);
        }
      }
    }
  }
  // epilogue
#pragma unroll
  for (int i = 0; i < 2; ++i) {
#pragma unroll
    for (int dt = 0; dt < 4; ++dt) {
#pragma unroll
      for (int r = 0; r < 4; ++r) {
        const int t = (2 * w + i) * 16 + quad * 4 + r;
        obuf[(rowT + t) * D_ + dt * 16 + col] = acc[i][dt][r];
      }
    }
    rs[i] += __shfl_xor(rs[i], 16);
    rs[i] += __shfl_xor(rs[i], 32);
  }
  if (lane < 16) {
    const size_t nbase = (size_t)(c * BH_ + bh) * CH_ + h2 * 128;
    nrmbuf[nbase + (2 * w + 0) * 16 + lane] = rs[0];
    nrmbuf[nbase + (2 * w + 1) * 16 + lane] = rs[1];
  }
}

// ---------------------------------------------------------------------------
// Hist + finalize: block = (c, bh, half128). bf16 pq/fq staged to f32 LDS.
// ---------------------------------------------------------------------------
__global__ __launch_bounds__(256) void k_hist(
    const unsigned short* __restrict__ pqb, const unsigned short* __restrict__ fqb,
    const unsigned short* __restrict__ kvch, const float* __restrict__ ksum,
    const float* __restrict__ nrmbuf, const float* __restrict__ obuf,
    unsigned short* __restrict__ obf) {
  __shared__ float pq[128][64];
  __shared__ float fq[128][8];
  __shared__ float kvt[64][65];
  __shared__ float kp[F_];
  __shared__ float nhs[128];
  const int half = blockIdx.x & 1;
  const int bh = (blockIdx.x >> 1) & (BH_ - 1);
  const int c = blockIdx.x >> 6;
  const int b = bh >> 4, h = bh & (H_ - 1);
  const int tid = threadIdx.x;
  const size_t rowQ = (size_t)bh * T_ + (size_t)c * CH_ + half * 128;
  {
    const int r0 = tid >> 3, gr = tid & 7;
#pragma unroll
    for (int pass = 0; pass < 4; ++pass) {
      const int r = pass * 32 + r0;
      const v8s pv = *(const v8s*)(pqb + (rowQ + r) * P_ + gr * 8);
#pragma unroll
      for (int j = 0; j < 8; ++j) pq[r][gr * 8 + j] = bf2f((unsigned short)pv[j]);
    }
    if (tid < 128) {
      const v8s fv = *(const v8s*)(fqb + (rowQ + tid) * M_);
#pragma unroll
      for (int j = 0; j < 8; ++j) fq[tid][j] = bf2f((unsigned short)fv[j]);
      *(float4*)(&kp[tid * 4]) =
          *(const float4*)(ksum + (size_t)(c * BH_ + bh) * F_ + tid * 4);
    }
  }
  __syncthreads();
  if (tid < 128) {
    const int t = tid;
    float fr[8];
#pragma unroll
    for (int mm = 0; mm < 8; ++mm) fr[mm] = fq[t][mm];
    float nh = 0.f;
#pragma unroll
    for (int p2 = 0; p2 < 64; ++p2) {
      float tmp = 0.f;
#pragma unroll
      for (int mm = 0; mm < 8; ++mm) tmp += fr[mm] * kp[p2 * 8 + mm];
      nh += pq[t][p2] * tmp;
    }
    nhs[t] = nh;
  }
  const int d = tid & 63, tg = tid >> 6;
  const int lr = tid >> 4, lc = (tid & 15) << 2;
  float ch[32];
#pragma unroll
  for (int k = 0; k < 32; ++k) ch[k] = 0.f;
  const size_t kvbase = (size_t)(c * BH_ + bh) * D_ * F_;
  for (int pmt = 0; pmt < 8; ++pmt) {
    __syncthreads();
#pragma unroll
    for (int rr = 0; rr < 64; rr += 16) {
      const ushort4 u = *(const ushort4*)(kvch + kvbase + (size_t)(rr + lr) * F_ + pmt * 64 + lc);
      kvt[rr + lr][lc + 0] = bf2f(u.x); kvt[rr + lr][lc + 1] = bf2f(u.y);
      kvt[rr + lr][lc + 2] = bf2f(u.z); kvt[rr + lr][lc + 3] = bf2f(u.w);
    }
    __syncthreads();
#pragma unroll
    for (int k = 0; k < 32; ++k) {
      const int t = tg * 32 + k;
      const float f0 = fq[t][0], f1 = fq[t][1], f2 = fq[t][2], f3 = fq[t][3];
      const float f4 = fq[t][4], f5 = fq[t][5], f6 = fq[t][6], f7 = fq[t][7];
      float a = 0.f;
#pragma unroll
      for (int pl = 0; pl < 8; ++pl) {
        const int pb = pl * 8;
        float tmp = f0 * kvt[d][pb + 0] + f1 * kvt[d][pb + 1] +
                    f2 * kvt[d][pb + 2] + f3 * kvt[d][pb + 3] +
                    f4 * kvt[d][pb + 4] + f5 * kvt[d][pb + 5] +
                    f6 * kvt[d][pb + 6] + f7 * kvt[d][pb + 7];
        a += pq[t][pmt * 8 + pl] * tmp;
      }
      ch[k] += a;
    }
  }
  const size_t nbase = (size_t)(c * BH_ + bh) * CH_ + half * 128;
#pragma unroll
  for (int k = 0; k < 32; ++k) {
    const int t = tg * 32 + k;
    const float nrm = nhs[t] + nrmbuf[nbase + t] + 1e-6f;
    const float val = (obuf[(rowQ + t) * D_ + d] + ch[k]) / nrm;
    obf[(size_t)(b * T_ + c * CH_ + half * 128 + t) * E_ + h * 64 + d] = f2bf(val);
  }
}

// ---------------------------------------------------------------------------
// Out GEMM via MFMA (unchanged)
// ---------------------------------------------------------------------------
__global__ __launch_bounds__(256) void k_out_mfma(
    const unsigned short* __restrict__ ob, const unsigned short* __restrict__ wb,
    const float* __restrict__ bias, float* __restrict__ out) {
  __shared__ __align__(16) unsigned short As[128 * LDSA];
  __shared__ __align__(16) unsigned short Bs[128 * LDSA];
  const int bt0 = blockIdx.x * 128, j0 = blockIdx.y * 128;
  const int tid = threadIdx.x;
  const int lane = tid & 63, wave = tid >> 6;
  const int wm = (wave & 1) * 64, wn = (wave >> 1) * 64;
  const int col = lane & 15, quad = lane >> 4;
  f32x4 acc[4][4] = {};
  const int sr = tid >> 3, sg = tid & 7;

  for (int k0 = 0; k0 < E_; k0 += 64) {
    __syncthreads();
#pragma unroll
    for (int it = 0; it < 4; ++it) {
      const int r = it * 32 + sr;
      *(v8s*)&As[r * LDSA + sg * 8] =
          *(const v8s*)(ob + (size_t)(bt0 + r) * E_ + k0 + sg * 8);
      *(v8s*)&Bs[r * LDSA + sg * 8] =
          *(const v8s*)(wb + (size_t)(j0 + r) * E_ + k0 + sg * 8);
    }
    __syncthreads();
#pragma unroll
    for (int kk = 0; kk < 2; ++kk) {
      v8s af[4], bfr[4];
#pragma unroll
      for (int i = 0; i < 4; ++i) {
        af[i] = *(const v8s*)&As[(wm + i * 16 + col) * LDSA + kk * 32 + quad * 8];
        bfr[i] = *(const v8s*)&Bs[(wn + i * 16 + col) * LDSA + kk * 32 + quad * 8];
      }
#pragma unroll
      for (int i = 0; i < 4; ++i)
#pragma unroll
        for (int j = 0; j < 4; ++j)
          acc[i][j] = __builtin_amdgcn_mfma_f32_16x16x32_bf16(af[i], bfr[j], acc[i][j], 0, 0, 0);
    }
  }
#pragma unroll
  for (int j = 0; j < 4; ++j) {
    const int n = j0 + wn + j * 16 + col;
    const float bv = bias[n];
#pragma unroll
    for (int i = 0; i < 4; ++i) {
      const int mbase = bt0 + wm + i * 16 + quad * 4;
#pragma unroll
      for (int r = 0; r < 4; ++r)
        out[(size_t)(mbase + r) * E_ + n] = acc[i][j][r] + bv;
    }
  }
}

// ---------------------------------------------------------------------------
extern "C" void kernel_launch(void* const* d_in, const int* in_sizes, int n_in,
                              void* d_out, int out_size, void* d_ws, size_t ws_size,
                              hipStream_t stream) {
  (void)in_sizes; (void)n_in; (void)out_size; (void)ws_size;
  const float* x      = (const float*)d_in[0];
  const float* qkv_w  = (const float*)d_in[1];
  const float* qkv_b  = (const float*)d_in[2];
  const float* out_w  = (const float*)d_in[3];
  const float* out_b  = (const float*)d_in[4];
  const float* omega  = (const float*)d_in[5];
  const float* poly_w = (const float*)d_in[6];
  const float* qnod   = (const float*)d_in[7];
  const float* qwt    = (const float*)d_in[8];
  float* ws = (float*)d_ws;
  float* qb   = ws + OFF_Q;
  float* kb   = ws + OFF_K;
  float* vb   = ws + OFF_V;
  unsigned short* fqb = (unsigned short*)(ws + OFF_FQ);
  unsigned short* fkb = (unsigned short*)(ws + OFF_FK);
  float* ksb  = ws + OFF_KS;
  float* nrmb = ws + OFF_NRM;
  float* ob   = ws + OFF_O;
  unsigned short* kvb = (unsigned short*)(ws + OFF_KV);
  unsigned short* pqb = kvb + 16777216;           // polyq bf16
  unsigned short* pkb = pqb + SZ_BHTD;            // polyk bf16
  // pre-qkv overlays (die before k_feat writes pqb/pkb):
  unsigned short* xhi  = kvb;
  unsigned short* xlo  = kvb + SZ_BHTD;
  unsigned short* wqkv = kvb + 2 * SZ_BHTD;
  // post-feat / post-sintra overlays:
  unsigned short* obf   = (unsigned short*)kb;    // o bf16 (bt,e), over dead raw-k
  unsigned short* woutb = (unsigned short*)vb;    // out_w bf16, over dead v
  float* outp = (float*)d_out;

  hipLaunchKernelGGL(k_split_x, dim3(8192), dim3(256), 0, stream, x, xhi, xlo);
  hipLaunchKernelGGL(k_cast_w, dim3(3072), dim3(256), 0, stream, qkv_w, wqkv);
  hipLaunchKernelGGL(k_qkv_mfma, dim3(BT_ / 128, 3 * E_ / 128), dim3(256), 0, stream,
                     xhi, xlo, wqkv, qkv_b, qb, kb, vb);
  hipLaunchKernelGGL(k_feat, dim3(2048), dim3(256), 0, stream,
                     qb, poly_w, omega, qnod, qwt, pqb, fqb);
  hipLaunchKernelGGL(k_feat, dim3(2048), dim3(256), 0, stream,
                     kb, poly_w, omega, qnod, qwt, pkb, fkb);
  hipLaunchKernelGGL(k_phaseA, dim3(NC_ * BH_), dim3(512), 0, stream,
                     pkb, fkb, vb, kvb, ksb);
  hipLaunchKernelGGL(k_scan_kv, dim3(4096), dim3(256), 0, stream, kvb);
  hipLaunchKernelGGL(k_scan_ks, dim3(64), dim3(256), 0, stream, ksb);
  hipLaunchKernelGGL(k_sintra, dim3(BH_ * 32), dim3(256), 0, stream,
                     pqb, fqb, pkb, fkb, vb, ob, nrmb);
  hipLaunchKernelGGL(k_cast_w, dim3(1024), dim3(256), 0, stream, out_w, woutb);
  hipLaunchKernelGGL(k_hist, dim3(NC_ * BH_ * 2), dim3(256), 0, stream,
                     pqb, fqb, kvb, ksb, nrmb, ob, obf);
  hipLaunchKernelGGL(k_out_mfma, dim3(BT_ / 128, E_ / 128), dim3(256), 0, stream,
                     obf, woutb, out_b, outp);
}

// Round 5
// 515.626 us; speedup vs baseline: 3.9129x; 1.4761x over previous
//
#include <hip/hip_runtime.h>
#include <math.h>

#define B_ 2
#define T_ 4096
#define E_ 1024
#define H_ 16
#define D_ 64
#define P_ 64
#define M_ 8
#define CH_ 256
#define NC_ 16
#define F_ 512
#define BH_ 32
#define BT_ 8192

// ---- workspace layout ----
static constexpr size_t SZ_BHTD = (size_t)B_ * H_ * T_ * D_;     // 8,388,608
static constexpr size_t SZ_PRF  = (size_t)B_ * H_ * T_ * M_;     // 1,048,576 (region in f32 units; holds bf16)
static constexpr size_t SZ_KS   = (size_t)NC_ * BH_ * F_;        // 262,144
static constexpr size_t SZ_NRM  = (size_t)NC_ * BH_ * CH_;       // 131,072
static constexpr size_t SZ_KV_E = 33554432;                      // bf16 region: kv | polyq_bf | polyk_bf

static constexpr size_t OFF_Q   = 0;
static constexpr size_t OFF_K   = OFF_Q + SZ_BHTD;
static constexpr size_t OFF_V   = OFF_K + SZ_BHTD;
static constexpr size_t OFF_FQ  = OFF_V + SZ_BHTD;
static constexpr size_t OFF_FK  = OFF_FQ + SZ_PRF;
static constexpr size_t OFF_KS  = OFF_FK + SZ_PRF;
static constexpr size_t OFF_NRM = OFF_KS + SZ_KS;
static constexpr size_t OFF_O   = OFF_NRM + SZ_NRM;
static constexpr size_t OFF_KV  = OFF_O + SZ_BHTD;
// total = OFF_KV*4 + SZ_KV_E*2 = 211,288,064 B (~201.5 MiB)

__device__ __forceinline__ float bf2f(unsigned short u) {
  union { unsigned u32; float f; } x; x.u32 = ((unsigned)u) << 16; return x.f;
}
__device__ __forceinline__ unsigned short f2bf(float f) {
  union { float f; unsigned u; } x; x.f = f;
  unsigned r = x.u + 0x7fffu + ((x.u >> 16) & 1u);
  return (unsigned short)(r >> 16);
}

typedef short v8s __attribute__((ext_vector_type(8)));
typedef float f32x4 __attribute__((ext_vector_type(4)));
#define LDSA 72   // GEMM LDS stride (bf16)

// ---------------------------------------------------------------------------
__global__ __launch_bounds__(256) void k_split_x(
    const float* __restrict__ x, unsigned short* __restrict__ hi,
    unsigned short* __restrict__ lo) {
  const size_t i4 = ((size_t)blockIdx.x * 256 + threadIdx.x) * 4;
  const float4 v = *(const float4*)(x + i4);
  ushort4 h, l;
  h.x = f2bf(v.x); l.x = f2bf(v.x - bf2f(h.x));
  h.y = f2bf(v.y); l.y = f2bf(v.y - bf2f(h.y));
  h.z = f2bf(v.z); l.z = f2bf(v.z - bf2f(h.z));
  h.w = f2bf(v.w); l.w = f2bf(v.w - bf2f(h.w));
  *(ushort4*)(hi + i4) = h;
  *(ushort4*)(lo + i4) = l;
}

__global__ __launch_bounds__(256) void k_cast_w(
    const float* __restrict__ w, unsigned short* __restrict__ wb) {
  const size_t i4 = ((size_t)blockIdx.x * 256 + threadIdx.x) * 4;
  const float4 v = *(const float4*)(w + i4);
  ushort4 h;
  h.x = f2bf(v.x); h.y = f2bf(v.y); h.z = f2bf(v.z); h.w = f2bf(v.w);
  *(ushort4*)(wb + i4) = h;
}

// ---------------------------------------------------------------------------
// QKV GEMM via MFMA, split-bf16 A, bf16 B. (unchanged)
// ---------------------------------------------------------------------------
__global__ __launch_bounds__(256) void k_qkv_mfma(
    const unsigned short* __restrict__ xhi, const unsigned short* __restrict__ xlo,
    const unsigned short* __restrict__ wb, const float* __restrict__ bias,
    float* __restrict__ qb, float* __restrict__ kb, float* __restrict__ vb) {
  __shared__ __align__(16) unsigned short Ah[128 * LDSA];
  __shared__ __align__(16) unsigned short Al[128 * LDSA];
  __shared__ __align__(16) unsigned short Bs[128 * LDSA];
  const int bt0 = blockIdx.x * 128, j0 = blockIdx.y * 128;
  const int tid = threadIdx.x;
  const int lane = tid & 63, wave = tid >> 6;
  const int wm = (wave & 1) * 64, wn = (wave >> 1) * 64;
  const int col = lane & 15, quad = lane >> 4;
  f32x4 acc[4][4] = {};
  const int sr = tid >> 3, sg = tid & 7;

  for (int k0 = 0; k0 < E_; k0 += 64) {
    __syncthreads();
#pragma unroll
    for (int it = 0; it < 4; ++it) {
      const int r = it * 32 + sr;
      const size_t ga = (size_t)(bt0 + r) * E_ + k0 + sg * 8;
      *(v8s*)&Ah[r * LDSA + sg * 8] = *(const v8s*)(xhi + ga);
      *(v8s*)&Al[r * LDSA + sg * 8] = *(const v8s*)(xlo + ga);
      *(v8s*)&Bs[r * LDSA + sg * 8] =
          *(const v8s*)(wb + (size_t)(j0 + r) * E_ + k0 + sg * 8);
    }
    __syncthreads();
#pragma unroll
    for (int kk = 0; kk < 2; ++kk) {
      v8s ah[4], al[4], bfr[4];
#pragma unroll
      for (int i = 0; i < 4; ++i) {
        const int mo = (wm + i * 16 + col) * LDSA + kk * 32 + quad * 8;
        ah[i] = *(const v8s*)&Ah[mo];
        al[i] = *(const v8s*)&Al[mo];
        bfr[i] = *(const v8s*)&Bs[(wn + i * 16 + col) * LDSA + kk * 32 + quad * 8];
      }
#pragma unroll
      for (int i = 0; i < 4; ++i)
#pragma unroll
        for (int j = 0; j < 4; ++j) {
          acc[i][j] = __builtin_amdgcn_mfma_f32_16x16x32_bf16(ah[i], bfr[j], acc[i][j], 0, 0, 0);
          acc[i][j] = __builtin_amdgcn_mfma_f32_16x16x32_bf16(al[i], bfr[j], acc[i][j], 0, 0, 0);
        }
    }
  }
#pragma unroll
  for (int j = 0; j < 4; ++j) {
    const int n = j0 + wn + j * 16 + col;
    const int sec = n >> 10, nn = n & 1023, h = nn >> 6, dd = nn & 63;
    float* dst = (sec == 0) ? qb : ((sec == 1) ? kb : vb);
    const float bv = bias[n];
#pragma unroll
    for (int i = 0; i < 4; ++i) {
      const int mbase = bt0 + wm + i * 16 + quad * 4;
#pragma unroll
      for (int r = 0; r < 4; ++r) {
        const int m = mbase + r;
        const int b = m >> 12, t = m & (T_ - 1);
        dst[((size_t)(b * H_ + h) * T_ + t) * D_ + dd] = acc[i][j][r] + bv;
      }
    }
  }
}

// ---------------------------------------------------------------------------
// Features: l2norm, poly -> bf16, prf -> bf16. (unchanged)
// ---------------------------------------------------------------------------
__global__ __launch_bounds__(256) void k_feat(
    const float* __restrict__ xin, const float* __restrict__ poly_w,
    const float* __restrict__ omega, const float* __restrict__ qnod,
    const float* __restrict__ qwt, unsigned short* __restrict__ poly_bf,
    unsigned short* __restrict__ prf_bf) {
  __shared__ float xs[64][65];
  __shared__ float pw[64][64];
  __shared__ float om[64][8];
  const int blk = blockIdx.x;
  const int bh = blk >> 6;
  const int t0 = (blk & 63) * 64;
  const int h = bh & (H_ - 1);
  const int tid = threadIdx.x;
  const int lr = tid >> 4, lc = (tid & 15) << 2;
#pragma unroll
  for (int rr = 0; rr < 64; rr += 16) {
    float4 v = *(const float4*)(xin + ((size_t)bh * T_ + t0 + rr + lr) * D_ + lc);
    xs[rr + lr][lc + 0] = v.x; xs[rr + lr][lc + 1] = v.y;
    xs[rr + lr][lc + 2] = v.z; xs[rr + lr][lc + 3] = v.w;
    *(float4*)(&pw[rr + lr][lc]) =
        *(const float4*)(poly_w + (size_t)h * D_ * P_ + (size_t)(rr + lr) * P_ + lc);
  }
  if (tid < 128) {
    *(float4*)(&om[tid >> 1][(tid & 1) * 4]) =
        *(const float4*)(omega + (size_t)h * D_ * M_ + (size_t)(tid >> 1) * M_ + (tid & 1) * 4);
  }
  __syncthreads();
  const int wv = tid >> 6, lane = tid & 63;
  for (int tt = wv * 16; tt < wv * 16 + 16; ++tt) {
    float xv = xs[tt][lane];
    float ssum = xv * xv;
#pragma unroll
    for (int off = 32; off > 0; off >>= 1) ssum += __shfl_xor(ssum, off);
    const float rn = 1.0f / fmaxf(sqrtf(ssum), 1e-12f);
    xs[tt][lane] = xv * rn;
  }
  __syncthreads();
  const int p = tid & 63, tg = tid >> 6;
  for (int k = 0; k < 16; ++k) {
    const int t = tg * 16 + k;
    float a = 0.f;
#pragma unroll
    for (int d = 0; d < 64; ++d) a += xs[t][d] * pw[d][p];
    poly_bf[((size_t)bh * T_ + t0 + t) * P_ + p] = f2bf(a * a * 0.125f);
  }
  const float s0 = qnod[0];
  const float sq2 = sqrtf(fmaxf(2.f * s0, 0.f));
  const float scale = sqrtf(fmaxf(qwt[0], 0.f)) * 0.3535533905932738f;
  const int m = tid & 7, tq = tid >> 3;
#pragma unroll
  for (int rep = 0; rep < 2; ++rep) {
    const int t = tq + rep * 32;
    float a = 0.f;
#pragma unroll
    for (int d = 0; d < 64; ++d) a += xs[t][d] * om[d][m];
    float z = fminf(fmaxf(a * sq2 - s0, -20.f), 20.f);
    prf_bf[((size_t)bh * T_ + t0 + t) * M_ + m] = f2bf(expf(z) * scale);
  }
}

// ---------------------------------------------------------------------------
// Phase A via MFMA: kv[d][pm] = sum_t V^T(A) x KF^T(B). KF^T fragments are
// generated in registers from pkT/fkT LDS slabs (rank-1). ksum rides along.
// Block = (c,bh), 512 threads, 8 waves x (4 m-tiles x 4 n-tiles).
// ---------------------------------------------------------------------------
__global__ __launch_bounds__(512) void k_phaseA(
    const unsigned short* __restrict__ pkb, const unsigned short* __restrict__ fkb,
    const float* __restrict__ vbuf, unsigned short* __restrict__ kvch,
    float* __restrict__ ksum) {
  __shared__ __align__(16) unsigned short VT[64 * 72];   // [d][t]  9,216 B
  __shared__ __align__(16) unsigned short pkT[64 * 72];  // [p][t]  9,216 B
  __shared__ __align__(16) unsigned short fkT[8 * 72];   // [m][t]  1,152 B
  const int bh = blockIdx.x & (BH_ - 1);
  const int c = blockIdx.x >> 5;
  const size_t rowC = (size_t)bh * T_ + (size_t)c * CH_;
  const int tid = threadIdx.x, lane = tid & 63, w = tid >> 6;
  const int col = lane & 15, quad = lane >> 4;
  const int nb = w * 64;               // wave's pm base (8 waves x 64)
  f32x4 acc[4][4] = {};
  float ks[4] = {0.f, 0.f, 0.f, 0.f};

  for (int st = 0; st < 4; ++st) {
    const size_t t0 = rowC + st * 64;
    __syncthreads();
#pragma unroll
    for (int ps = 0; ps < 2; ++ps) {
      const int idx = ps * 512 + tid;
      const int t = idx >> 4, dg = (idx & 15) * 4;
      const float4 v = *(const float4*)(vbuf + (t0 + t) * D_ + dg);
      VT[(dg + 0) * 72 + t] = f2bf(v.x);
      VT[(dg + 1) * 72 + t] = f2bf(v.y);
      VT[(dg + 2) * 72 + t] = f2bf(v.z);
      VT[(dg + 3) * 72 + t] = f2bf(v.w);
    }
    {
      const int t = tid >> 3, pg = (tid & 7) * 8;
      const v8s pv = *(const v8s*)(pkb + (t0 + t) * P_ + pg);
#pragma unroll
      for (int j = 0; j < 8; ++j) pkT[(pg + j) * 72 + t] = (unsigned short)pv[j];
    }
    if (tid < 64) {
      const v8s fv = *(const v8s*)(fkb + (t0 + tid) * M_);
#pragma unroll
      for (int j = 0; j < 8; ++j) fkT[j * 72 + tid] = (unsigned short)fv[j];
    }
    __syncthreads();
#pragma unroll
    for (int kk = 0; kk < 2; ++kk) {
      v8s a[4];
#pragma unroll
      for (int mt = 0; mt < 4; ++mt)
        a[mt] = *(const v8s*)&VT[(mt * 16 + col) * 72 + kk * 32 + quad * 8];
#pragma unroll
      for (int nt = 0; nt < 4; ++nt) {
        const int pm = nb + nt * 16 + col;
        const int p = pm >> 3, m8 = pm & 7;
        const v8s pkv = *(const v8s*)&pkT[p * 72 + kk * 32 + quad * 8];
        const v8s fkv = *(const v8s*)&fkT[m8 * 72 + kk * 32 + quad * 8];
        v8s bfrag;
        float kss = 0.f;
#pragma unroll
        for (int j = 0; j < 8; ++j) {
          const float v = bf2f((unsigned short)pkv[j]) * bf2f((unsigned short)fkv[j]);
          kss += v;
          bfrag[j] = (short)f2bf(v);
        }
        ks[nt] += kss;
#pragma unroll
        for (int mt = 0; mt < 4; ++mt)
          acc[mt][nt] = __builtin_amdgcn_mfma_f32_16x16x32_bf16(a[mt], bfrag, acc[mt][nt], 0, 0, 0);
      }
    }
  }
  const size_t base = (size_t)(c * BH_ + bh) * D_ * F_;
#pragma unroll
  for (int nt = 0; nt < 4; ++nt) {
    const int pm = nb + nt * 16 + col;
#pragma unroll
    for (int mt = 0; mt < 4; ++mt) {
#pragma unroll
      for (int r = 0; r < 4; ++r) {
        const int d = mt * 16 + quad * 4 + r;
        kvch[base + (size_t)d * F_ + pm] = f2bf(acc[mt][nt][r]);
      }
    }
    float kv_ = ks[nt];
    kv_ += __shfl_xor(kv_, 16);
    kv_ += __shfl_xor(kv_, 32);
    if (quad == 0) ksum[(size_t)(c * BH_ + bh) * F_ + pm] = kv_;
  }
}

// ---------------------------------------------------------------------------
__global__ __launch_bounds__(256) void k_scan_kv(unsigned short* __restrict__ kvch) {
  const size_t s = (size_t)blockIdx.x * 256 + threadIdx.x;
  const size_t stride = (size_t)BH_ * D_ * F_;
  unsigned short v[NC_];
#pragma unroll
  for (int c = 0; c < NC_; ++c) v[c] = kvch[(size_t)c * stride + s];
  float run = 0.f;
#pragma unroll
  for (int c = 0; c < NC_; ++c) {
    const float t = bf2f(v[c]);
    kvch[(size_t)c * stride + s] = f2bf(run);
    run += t;
  }
}

__global__ __launch_bounds__(256) void k_scan_ks(float* __restrict__ ksum) {
  const int s = blockIdx.x * 256 + threadIdx.x;
  const int stride = BH_ * F_;
  float v[NC_];
#pragma unroll
  for (int c = 0; c < NC_; ++c) v[c] = ksum[c * stride + s];
  float run = 0.f;
#pragma unroll
  for (int c = 0; c < NC_; ++c) {
    const float t = v[c];
    ksum[c * stride + s] = run;
    run += t;
  }
}

// ---------------------------------------------------------------------------
// Fused scores+intra via MFMA (unchanged from round 4)
// ---------------------------------------------------------------------------
__global__ __launch_bounds__(256) void k_sintra(
    const unsigned short* __restrict__ pqb, const unsigned short* __restrict__ fqb,
    const unsigned short* __restrict__ pkb, const unsigned short* __restrict__ fkb,
    const float* __restrict__ vbuf, float* __restrict__ obuf,
    float* __restrict__ nrmbuf) {
  __shared__ __align__(16) unsigned short S_lds[128 * 136];
  __shared__ __align__(16) unsigned short VT[64 * 136];
  __shared__ float fk_lds[128][8];
  const int bh = blockIdx.x & (BH_ - 1);
  const int tq = blockIdx.x >> 5;
  const int c = tq >> 1, h2 = tq & 1;
  const size_t rowT = (size_t)bh * T_ + (size_t)tq * 128;
  const size_t rowC = (size_t)bh * T_ + (size_t)c * CH_;
  const int tid = threadIdx.x, lane = tid & 63, w = tid >> 6;
  const int col = lane & 15, quad = lane >> 4;

  v8s bq[2][2];
  float fqr[2][8];
#pragma unroll
  for (int i = 0; i < 2; ++i) {
    const size_t qrow = rowT + (2 * w + i) * 16 + col;
    bq[i][0] = *(const v8s*)(pqb + qrow * P_ + quad * 8);
    bq[i][1] = *(const v8s*)(pqb + qrow * P_ + 32 + quad * 8);
    const v8s fv = *(const v8s*)(fqb + qrow * M_);
#pragma unroll
    for (int j = 0; j < 8; ++j) fqr[i][j] = bf2f((unsigned short)fv[j]);
  }
  f32x4 acc[2][4] = {};
  float rs[2] = {0.f, 0.f};

  const int vd = tid & 63, vg = tid >> 6;

  for (int sl = 0; sl <= h2; ++sl) {
    const size_t rowS = rowC + (size_t)sl * 128;
    __syncthreads();
    if (tid < 128) {
      const v8s fv = *(const v8s*)(fkb + (rowS + tid) * M_);
#pragma unroll
      for (int j = 0; j < 8; ++j) fk_lds[tid][j] = bf2f((unsigned short)fv[j]);
    }
#pragma unroll
    for (int j8 = 0; j8 < 4; ++j8) {
      const int s0 = vg * 32 + j8 * 8;
      unsigned short pkt[8];
#pragma unroll
      for (int k = 0; k < 8; ++k)
        pkt[k] = f2bf(vbuf[(rowS + s0 + k) * D_ + vd]);
      v8s pv;
#pragma unroll
      for (int k = 0; k < 8; ++k) pv[k] = (short)pkt[k];
      *(v8s*)&VT[vd * 136 + s0] = pv;
    }
    __syncthreads();
#pragma unroll
    for (int i = 0; i < 2; ++i) {
      const int tt = 2 * w + i;
      const int t_rel = h2 * 128 + tt * 16 + col;
      for (int si = 0; si < 8; ++si) {
        const size_t ar = rowS + si * 16 + col;
        const v8s a0 = *(const v8s*)(pkb + ar * P_ + quad * 8);
        const v8s a1 = *(const v8s*)(pkb + ar * P_ + 32 + quad * 8);
        f32x4 sp = {};
        sp = __builtin_amdgcn_mfma_f32_16x16x32_bf16(a0, bq[i][0], sp, 0, 0, 0);
        sp = __builtin_amdgcn_mfma_f32_16x16x32_bf16(a1, bq[i][1], sp, 0, 0, 0);
        ushort4 pk4;
        float partial = 0.f;
#pragma unroll
        for (int r = 0; r < 4; ++r) {
          const int s_in = si * 16 + quad * 4 + r;
          const float4 f0 = *(const float4*)&fk_lds[s_in][0];
          const float4 f1 = *(const float4*)&fk_lds[s_in][4];
          const float sm = f0.x * fqr[i][0] + f0.y * fqr[i][1] + f0.z * fqr[i][2] +
                           f0.w * fqr[i][3] + f1.x * fqr[i][4] + f1.y * fqr[i][5] +
                           f1.z * fqr[i][6] + f1.w * fqr[i][7];
          float val = sp[r] * sm;
          const int s_rel = sl * 128 + s_in;
          val = (s_rel <= t_rel) ? val : 0.f;
          partial += val;
          ((unsigned short*)&pk4)[r] = f2bf(val);
        }
        rs[i] += partial;
        *(ushort4*)&S_lds[(tt * 16 + col) * 136 + si * 16 + quad * 4] = pk4;
      }
    }
    __syncthreads();
#pragma unroll
    for (int i = 0; i < 2; ++i) {
      const int tt = 2 * w + i;
#pragma unroll
      for (int kk = 0; kk < 4; ++kk) {
        const v8s sa = *(const v8s*)&S_lds[(tt * 16 + col) * 136 + kk * 32 + quad * 8];
#pragma unroll
        for (int dt = 0; dt < 4; ++dt) {
          const v8s vb8 = *(const v8s*)&VT[(dt * 16 + col) * 136 + kk * 32 + quad * 8];
          acc[i][dt] = __builtin_amdgcn_mfma_f32_16x16x32_bf16(sa, vb8, acc[i][dt], 0, 0, 0);
        }
      }
    }
  }
#pragma unroll
  for (int i = 0; i < 2; ++i) {
#pragma unroll
    for (int dt = 0; dt < 4; ++dt) {
#pragma unroll
      for (int r = 0; r < 4; ++r) {
        const int t = (2 * w + i) * 16 + quad * 4 + r;
        obuf[(rowT + t) * D_ + dt * 16 + col] = acc[i][dt][r];
      }
    }
    rs[i] += __shfl_xor(rs[i], 16);
    rs[i] += __shfl_xor(rs[i], 32);
  }
  if (lane < 16) {
    const size_t nbase = (size_t)(c * BH_ + bh) * CH_ + h2 * 128;
    nrmbuf[nbase + (2 * w + 0) * 16 + lane] = rs[0];
    nrmbuf[nbase + (2 * w + 1) * 16 + lane] = rs[1];
  }
}

// ---------------------------------------------------------------------------
// Hist via MFMA: ch[t][d] = QF(A, generated rank-1) x KV^T(B, raw bf16).
// nh[t] accumulated during QF generation against ksum-prefix. Finalize + obf.
// Block = (c,bh,half): 1024 blocks, 256 threads, LDS ~30 KB.
// ---------------------------------------------------------------------------
__global__ __launch_bounds__(256) void k_hist(
    const unsigned short* __restrict__ pqb, const unsigned short* __restrict__ fqb,
    const unsigned short* __restrict__ kvch, const float* __restrict__ ksum,
    const float* __restrict__ nrmbuf, const float* __restrict__ obuf,
    unsigned short* __restrict__ obf) {
  __shared__ __align__(16) unsigned short QF_lds[128 * 72];  // 18,432 B
  __shared__ __align__(16) unsigned short KV_lds[64 * 72];   //  9,216 B
  __shared__ float kp_lds[F_];                               //  2,048 B
  __shared__ float nhs[128];                                 //    512 B
  const int half = blockIdx.x & 1;
  const int bh = (blockIdx.x >> 1) & (BH_ - 1);
  const int c = blockIdx.x >> 6;
  const int b = bh >> 4, h = bh & (H_ - 1);
  const int tid = threadIdx.x, lane = tid & 63, w = tid >> 6;
  const int col = lane & 15, quad = lane >> 4;
  const size_t rowQ = (size_t)bh * T_ + (size_t)c * CH_ + half * 128;
  const size_t kvbase = (size_t)(c * BH_ + bh) * D_ * F_;

  // per-thread row assignment for QF generation
  const int tr = tid >> 1, side = tid & 1;   // row t, p-half
  float fqr[8];
  {
    const v8s fv = *(const v8s*)(fqb + (rowQ + tr) * M_);
#pragma unroll
    for (int j = 0; j < 8; ++j) fqr[j] = bf2f((unsigned short)fv[j]);
    if (tid < 128)
      *(float4*)(&kp_lds[tid * 4]) =
          *(const float4*)(ksum + (size_t)(c * BH_ + bh) * F_ + tid * 4);
  }
  f32x4 acc[2][4] = {};
  float nh_part = 0.f;
  const int gr = tid & 7, d0 = tid >> 3;     // KV staging

  for (int pmt = 0; pmt < 8; ++pmt) {
    __syncthreads();
    // stage KV k-tile (raw bf16)
#pragma unroll
    for (int pp = 0; pp < 2; ++pp) {
      const int d = d0 + pp * 32;
      *(v8s*)&KV_lds[d * 72 + gr * 8] =
          *(const v8s*)(kvch + kvbase + (size_t)d * F_ + pmt * 64 + gr * 8);
    }
    // generate QF k-tile: QF[t][p*8+m] = pq[t][pmt*8+p] * fq[t][m]
    {
      const v8s pq8 = *(const v8s*)(pqb + (rowQ + tr) * P_ + pmt * 8);
#pragma unroll
      for (int pp = 0; pp < 4; ++pp) {
        const int pl = side * 4 + pp;
        const float pqf = bf2f((unsigned short)pq8[pl]);
        const int kb_ = (pmt * 8 + pl) * 8;
        v8s o;
#pragma unroll
        for (int j = 0; j < 8; ++j) {
          const float v = pqf * fqr[j];
          nh_part += v * kp_lds[kb_ + j];
          o[j] = (short)f2bf(v);
        }
        *(v8s*)&QF_lds[tr * 72 + pl * 8] = o;
      }
    }
    __syncthreads();
    // MFMA: wave w -> m-tiles {2w, 2w+1}, n-tiles 0..3
#pragma unroll
    for (int kk = 0; kk < 2; ++kk) {
      v8s a[2], bb[4];
#pragma unroll
      for (int i = 0; i < 2; ++i)
        a[i] = *(const v8s*)&QF_lds[((2 * w + i) * 16 + col) * 72 + kk * 32 + quad * 8];
#pragma unroll
      for (int j = 0; j < 4; ++j)
        bb[j] = *(const v8s*)&KV_lds[(j * 16 + col) * 72 + kk * 32 + quad * 8];
#pragma unroll
      for (int i = 0; i < 2; ++i)
#pragma unroll
        for (int j = 0; j < 4; ++j)
          acc[i][j] = __builtin_amdgcn_mfma_f32_16x16x32_bf16(a[i], bb[j], acc[i][j], 0, 0, 0);
    }
  }
  // nh: combine the two p-halves of each row
  {
    const float nh = nh_part + __shfl_xor(nh_part, 1);
    if (!(tid & 1)) nhs[tr] = nh;
  }
  __syncthreads();
  // epilogue
  const size_t nbase = (size_t)(c * BH_ + bh) * CH_ + half * 128;
#pragma unroll
  for (int i = 0; i < 2; ++i) {
#pragma unroll
    for (int r = 0; r < 4; ++r) {
      const int t = (2 * w + i) * 16 + quad * 4 + r;
      const float nrm = nhs[t] + nrmbuf[nbase + t] + 1e-6f;
      const float rcp = 1.0f / nrm;
#pragma unroll
      for (int j = 0; j < 4; ++j) {
        const int d = j * 16 + col;
        const float val = (obuf[(rowQ + t) * D_ + d] + acc[i][j][r]) * rcp;
        obf[(size_t)(b * T_ + c * CH_ + half * 128 + t) * E_ + h * 64 + d] = f2bf(val);
      }
    }
  }
}

// ---------------------------------------------------------------------------
// Out GEMM via MFMA (unchanged)
// ---------------------------------------------------------------------------
__global__ __launch_bounds__(256) void k_out_mfma(
    const unsigned short* __restrict__ ob, const unsigned short* __restrict__ wb,
    const float* __restrict__ bias, float* __restrict__ out) {
  __shared__ __align__(16) unsigned short As[128 * LDSA];
  __shared__ __align__(16) unsigned short Bs[128 * LDSA];
  const int bt0 = blockIdx.x * 128, j0 = blockIdx.y * 128;
  const int tid = threadIdx.x;
  const int lane = tid & 63, wave = tid >> 6;
  const int wm = (wave & 1) * 64, wn = (wave >> 1) * 64;
  const int col = lane & 15, quad = lane >> 4;
  f32x4 acc[4][4] = {};
  const int sr = tid >> 3, sg = tid & 7;

  for (int k0 = 0; k0 < E_; k0 += 64) {
    __syncthreads();
#pragma unroll
    for (int it = 0; it < 4; ++it) {
      const int r = it * 32 + sr;
      *(v8s*)&As[r * LDSA + sg * 8] =
          *(const v8s*)(ob + (size_t)(bt0 + r) * E_ + k0 + sg * 8);
      *(v8s*)&Bs[r * LDSA + sg * 8] =
          *(const v8s*)(wb + (size_t)(j0 + r) * E_ + k0 + sg * 8);
    }
    __syncthreads();
#pragma unroll
    for (int kk = 0; kk < 2; ++kk) {
      v8s af[4], bfr[4];
#pragma unroll
      for (int i = 0; i < 4; ++i) {
        af[i] = *(const v8s*)&As[(wm + i * 16 + col) * LDSA + kk * 32 + quad * 8];
        bfr[i] = *(const v8s*)&Bs[(wn + i * 16 + col) * LDSA + kk * 32 + quad * 8];
      }
#pragma unroll
      for (int i = 0; i < 4; ++i)
#pragma unroll
        for (int j = 0; j < 4; ++j)
          acc[i][j] = __builtin_amdgcn_mfma_f32_16x16x32_bf16(af[i], bfr[j], acc[i][j], 0, 0, 0);
    }
  }
#pragma unroll
  for (int j = 0; j < 4; ++j) {
    const int n = j0 + wn + j * 16 + col;
    const float bv = bias[n];
#pragma unroll
    for (int i = 0; i < 4; ++i) {
      const int mbase = bt0 + wm + i * 16 + quad * 4;
#pragma unroll
      for (int r = 0; r < 4; ++r)
        out[(size_t)(mbase + r) * E_ + n] = acc[i][j][r] + bv;
    }
  }
}

// ---------------------------------------------------------------------------
extern "C" void kernel_launch(void* const* d_in, const int* in_sizes, int n_in,
                              void* d_out, int out_size, void* d_ws, size_t ws_size,
                              hipStream_t stream) {
  (void)in_sizes; (void)n_in; (void)out_size; (void)ws_size;
  const float* x      = (const float*)d_in[0];
  const float* qkv_w  = (const float*)d_in[1];
  const float* qkv_b  = (const float*)d_in[2];
  const float* out_w  = (const float*)d_in[3];
  const float* out_b  = (const float*)d_in[4];
  const float* omega  = (const float*)d_in[5];
  const float* poly_w = (const float*)d_in[6];
  const float* qnod   = (const float*)d_in[7];
  const float* qwt    = (const float*)d_in[8];
  float* ws = (float*)d_ws;
  float* qb   = ws + OFF_Q;
  float* kb   = ws + OFF_K;
  float* vb   = ws + OFF_V;
  unsigned short* fqb = (unsigned short*)(ws + OFF_FQ);
  unsigned short* fkb = (unsigned short*)(ws + OFF_FK);
  float* ksb  = ws + OFF_KS;
  float* nrmb = ws + OFF_NRM;
  float* ob   = ws + OFF_O;
  unsigned short* kvb = (unsigned short*)(ws + OFF_KV);
  unsigned short* pqb = kvb + 16777216;
  unsigned short* pkb = pqb + SZ_BHTD;
  unsigned short* xhi  = kvb;
  unsigned short* xlo  = kvb + SZ_BHTD;
  unsigned short* wqkv = kvb + 2 * SZ_BHTD;
  unsigned short* obf   = (unsigned short*)kb;
  unsigned short* woutb = (unsigned short*)vb;
  float* outp = (float*)d_out;

  hipLaunchKernelGGL(k_split_x, dim3(8192), dim3(256), 0, stream, x, xhi, xlo);
  hipLaunchKernelGGL(k_cast_w, dim3(3072), dim3(256), 0, stream, qkv_w, wqkv);
  hipLaunchKernelGGL(k_qkv_mfma, dim3(BT_ / 128, 3 * E_ / 128), dim3(256), 0, stream,
                     xhi, xlo, wqkv, qkv_b, qb, kb, vb);
  hipLaunchKernelGGL(k_feat, dim3(2048), dim3(256), 0, stream,
                     qb, poly_w, omega, qnod, qwt, pqb, fqb);
  hipLaunchKernelGGL(k_feat, dim3(2048), dim3(256), 0, stream,
                     kb, poly_w, omega, qnod, qwt, pkb, fkb);
  hipLaunchKernelGGL(k_phaseA, dim3(NC_ * BH_), dim3(512), 0, stream,
                     pkb, fkb, vb, kvb, ksb);
  hipLaunchKernelGGL(k_scan_kv, dim3(4096), dim3(256), 0, stream, kvb);
  hipLaunchKernelGGL(k_scan_ks, dim3(64), dim3(256), 0, stream, ksb);
  hipLaunchKernelGGL(k_sintra, dim3(BH_ * 32), dim3(256), 0, stream,
                     pqb, fqb, pkb, fkb, vb, ob, nrmb);
  hipLaunchKernelGGL(k_cast_w, dim3(1024), dim3(256), 0, stream, out_w, woutb);
  hipLaunchKernelGGL(k_hist, dim3(NC_ * BH_ * 2), dim3(256), 0, stream,
                     pqb, fqb, kvb, ksb, nrmb, ob, obf);
  hipLaunchKernelGGL(k_out_mfma, dim3(BT_ / 128, E_ / 128), dim3(256), 0, stream,
                     obf, woutb, out_b, outp);
}